// Round 4
// baseline (71798.273 us; speedup 1.0000x reference)
//
#include <hip/hip_runtime.h>

#define SEQL 1024
#define EMB  2048
#define HID  2048
#define G4   8192   // 4*HID
#define NTAG 50
#define NWG  256

// ---------------------------------------------------------------------------
// Kernel 1: x_gates[t][n] = sum_k emb[seq[t]][k] * W_ih[n][k] + b_ih[n] + b_hh[n]
// f32 tiled GEMM, 128x128 tile, 256 threads, 8x8 micro-tile per thread.
// Also resets the grid-barrier counter for kernel 2 (runs before it on stream).
// ---------------------------------------------------------------------------
__global__ __launch_bounds__(256) void gemm_xgates(
    const int* __restrict__ seq, const float* __restrict__ emb,
    const float* __restrict__ Wih, const float* __restrict__ bih,
    const float* __restrict__ bhh, float* __restrict__ xg, int* __restrict__ ctr)
{
    if (blockIdx.x == 0 && blockIdx.y == 0 && threadIdx.x == 0) *ctr = 0;

    constexpr int BM = 128, BN = 128, BK = 32;
    __shared__ float As[BK][BM + 4];   // stored transposed: As[k][m]
    __shared__ float Bs[BK][BN + 4];
    __shared__ int   srow[BM];

    const int tid = threadIdx.x;
    const int bn = blockIdx.x, bm = blockIdx.y;

    if (tid < BM) srow[tid] = seq[bm * BM + tid];
    __syncthreads();

    const int tx = tid & 15, ty = tid >> 4;
    const int c4 = tid & 7;          // float4 column within BK
    const int r0 = tid >> 3;         // row 0..31 (4 batches of 32)

    float acc[8][8] = {};

    for (int k0 = 0; k0 < EMB; k0 += BK) {
        #pragma unroll
        for (int i = 0; i < 4; ++i) {
            const int r = r0 + 32 * i;
            float4 av = *(const float4*)(emb + (size_t)srow[r] * EMB + k0 + 4 * c4);
            As[4*c4+0][r] = av.x; As[4*c4+1][r] = av.y;
            As[4*c4+2][r] = av.z; As[4*c4+3][r] = av.w;
            float4 bv = *(const float4*)(Wih + (size_t)(bn * BN + r) * EMB + k0 + 4 * c4);
            Bs[4*c4+0][r] = bv.x; Bs[4*c4+1][r] = bv.y;
            Bs[4*c4+2][r] = bv.z; Bs[4*c4+3][r] = bv.w;
        }
        __syncthreads();
        #pragma unroll
        for (int kk = 0; kk < BK; ++kk) {
            float a[8], b[8];
            *(float4*)&a[0] = *(const float4*)&As[kk][8*ty];
            *(float4*)&a[4] = *(const float4*)&As[kk][8*ty+4];
            *(float4*)&b[0] = *(const float4*)&Bs[kk][8*tx];
            *(float4*)&b[4] = *(const float4*)&Bs[kk][8*tx+4];
            #pragma unroll
            for (int i = 0; i < 8; ++i)
                #pragma unroll
                for (int j = 0; j < 8; ++j)
                    acc[i][j] += a[i] * b[j];
        }
        __syncthreads();
    }

    const int gm = bm * BM + 8 * ty;
    const int gn = bn * BN + 8 * tx;
    float bb[8];
    #pragma unroll
    for (int j = 0; j < 8; ++j) bb[j] = bih[gn + j] + bhh[gn + j];
    #pragma unroll
    for (int i = 0; i < 8; ++i) {
        float4 o0, o1;
        o0.x = acc[i][0] + bb[0]; o0.y = acc[i][1] + bb[1];
        o0.z = acc[i][2] + bb[2]; o0.w = acc[i][3] + bb[3];
        o1.x = acc[i][4] + bb[4]; o1.y = acc[i][5] + bb[5];
        o1.z = acc[i][6] + bb[6]; o1.w = acc[i][7] + bb[7];
        *(float4*)(xg + (size_t)(gm + i) * G4 + gn)     = o0;
        *(float4*)(xg + (size_t)(gm + i) * G4 + gn + 4) = o1;
    }
}

// ---------------------------------------------------------------------------
// Kernel 2: persistent LSTM recurrence, 256 wgs x 512 threads (1 wg/CU).
// Weights live in LDS as bf16: wbf[wave][gate][2048] = 128 KB/CU — guaranteed
// on-chip, independent of the register allocator (R1-R3 all re-streamed the
// 64 MB W_hh from L3 every step: remat or scratch spill; 28-68 us/step).
// Wave w owns hidden unit j = 8g+w. Lane l reads weight chunks k=8(l+64r),
// 16B/lane stride -> conflict-free ds_read_b128. h read from global (L2/L3),
// 128 FMA + bf16 shifts, butterfly reduce, gates, c in-register,
// monotonic-counter grid barrier.
// ---------------------------------------------------------------------------
__device__ __forceinline__ float sigm_(float x) { return 1.0f / (1.0f + __expf(-x)); }
__device__ __forceinline__ float tanh_(float x) {
    float e = __expf(2.0f * x);
    return (e - 1.0f) / (e + 1.0f);
}
__device__ __forceinline__ ushort f2bf_rne(float f) {
    unsigned u = __float_as_uint(f);
    unsigned r = (u + 0x7fffu + ((u >> 16) & 1u)) >> 16;   // round-nearest-even
    return (ushort)r;
}
__device__ __forceinline__ float bflo(unsigned u) { return __uint_as_float(u << 16); }
__device__ __forceinline__ float bfhi(unsigned u) { return __uint_as_float(u & 0xffff0000u); }

__global__ __launch_bounds__(512, 1) void lstm_recur(
    const float* __restrict__ Whh, const float* __restrict__ xg,
    const float* __restrict__ Wtag, const float* __restrict__ btag,
    float* __restrict__ hbuf, float* __restrict__ tags, float* __restrict__ out,
    int* __restrict__ ctr)
{
    __shared__ ushort wbf[8][4][HID];   // 128 KB bf16 weights
    __shared__ float  sh_red[8];

    const int tid = threadIdx.x;
    const int wv  = tid >> 6;              // wave 0..7
    const int l   = tid & 63;              // lane
    const int j   = 8 * blockIdx.x + wv;   // hidden unit owned by this wave

    // One-time: load this wg's W_hh rows, convert f32->bf16 (RNE), store LDS.
    #pragma unroll
    for (int q = 0; q < 4; ++q) {
        const float* wr = Whh + (size_t)(q * HID + j) * HID;
        #pragma unroll
        for (int i = 0; i < 8; ++i) {
            const int c = l + 64 * i;               // float4 chunk index
            float4 v = *(const float4*)(wr + 4 * c);
            ushort4 b;
            b.x = f2bf_rne(v.x); b.y = f2bf_rne(v.y);
            b.z = f2bf_rne(v.z); b.w = f2bf_rne(v.w);
            *(ushort4*)&wbf[wv][q][4 * c] = b;
        }
    }
    __syncthreads();

    float c = 0.0f;

    // Prefetch xg for t = 0.
    float xg0 = xg[j];
    float xg1 = xg[j + HID];
    float xg2 = xg[j + 2 * HID];
    float xg3 = xg[j + 3 * HID];

    for (int t = 0; t < SEQL; ++t) {
        float s0 = 0.f, s1 = 0.f, s2 = 0.f, s3 = 0.f;
        if (t > 0) {
            const float* hp = hbuf + ((t + 1) & 1) * HID;
            #pragma unroll
            for (int r = 0; r < 4; ++r) {
                const int k0 = 8 * (l + 64 * r);
                float4 ha = *(const float4*)(hp + k0);
                float4 hb = *(const float4*)(hp + k0 + 4);
                uint4 w0 = *(const uint4*)&wbf[wv][0][k0];
                uint4 w1 = *(const uint4*)&wbf[wv][1][k0];
                uint4 w2 = *(const uint4*)&wbf[wv][2][k0];
                uint4 w3 = *(const uint4*)&wbf[wv][3][k0];
                s0 += bflo(w0.x)*ha.x + bfhi(w0.x)*ha.y + bflo(w0.y)*ha.z + bfhi(w0.y)*ha.w
                    + bflo(w0.z)*hb.x + bfhi(w0.z)*hb.y + bflo(w0.w)*hb.z + bfhi(w0.w)*hb.w;
                s1 += bflo(w1.x)*ha.x + bfhi(w1.x)*ha.y + bflo(w1.y)*ha.z + bfhi(w1.y)*ha.w
                    + bflo(w1.z)*hb.x + bfhi(w1.z)*hb.y + bflo(w1.w)*hb.z + bfhi(w1.w)*hb.w;
                s2 += bflo(w2.x)*ha.x + bfhi(w2.x)*ha.y + bflo(w2.y)*ha.z + bfhi(w2.y)*ha.w
                    + bflo(w2.z)*hb.x + bfhi(w2.z)*hb.y + bflo(w2.w)*hb.z + bfhi(w2.w)*hb.w;
                s3 += bflo(w3.x)*ha.x + bfhi(w3.x)*ha.y + bflo(w3.y)*ha.z + bfhi(w3.y)*ha.w
                    + bflo(w3.z)*hb.x + bfhi(w3.z)*hb.y + bflo(w3.w)*hb.z + bfhi(w3.w)*hb.w;
            }
        }
        #pragma unroll
        for (int m = 1; m < 64; m <<= 1) {
            s0 += __shfl_xor(s0, m);
            s1 += __shfl_xor(s1, m);
            s2 += __shfl_xor(s2, m);
            s3 += __shfl_xor(s3, m);
        }
        const float gi = sigm_(s0 + xg0);
        const float gf = sigm_(s1 + xg1);
        const float gg = tanh_(s2 + xg2);
        const float go = sigm_(s3 + xg3);
        c = gf * c + gi * gg;
        const float h = go * tanh_(c);
        if (l == 0) hbuf[(t & 1) * HID + j] = h;

        // Prefetch next step's xg BEFORE the barrier; latency hides under spin.
        const int tn = (t + 1 < SEQL) ? t + 1 : t;
        const size_t xb = (size_t)tn * G4 + j;
        xg0 = xg[xb];
        xg1 = xg[xb + HID];
        xg2 = xg[xb + 2 * HID];
        xg3 = xg[xb + 3 * HID];

        // ---- custom grid barrier (monotonic counter, no reset per step) ----
        __threadfence();                   // release: make h store visible
        __syncthreads();
        if (tid == 0) {
            atomicAdd(ctr, 1);
            const int target = NWG * (t + 1);
            while (__hip_atomic_load(ctr, __ATOMIC_RELAXED, __HIP_MEMORY_SCOPE_AGENT) < target)
                __builtin_amdgcn_s_sleep(1);
        }
        __syncthreads();
        __threadfence();                   // acquire: invalidate stale cache
    }

    // ---- tag projection: wgs 0..49 each compute one tag row ----
    const float* hfin = hbuf + HID;        // t=1023 wrote buffer 1
    if (blockIdx.x < NTAG) {
        float4 wv4 = *(const float4*)(Wtag + (size_t)blockIdx.x * HID + 4 * tid);
        float4 hv4 = *(const float4*)(hfin + 4 * tid);
        float part = wv4.x*hv4.x + wv4.y*hv4.y + wv4.z*hv4.z + wv4.w*hv4.w;
        #pragma unroll
        for (int m = 1; m < 64; m <<= 1) part += __shfl_xor(part, m);
        if (l == 0) sh_red[wv] = part;
        __syncthreads();
        if (tid == 0) {
            float s = 0.f;
            #pragma unroll
            for (int i = 0; i < 8; ++i) s += sh_red[i];
            tags[blockIdx.x] = s + btag[blockIdx.x];
        }
    }

    // ---- final barrier, then log_softmax on wg 0 / wave 0 ----
    __threadfence();
    __syncthreads();
    if (tid == 0) {
        atomicAdd(ctr, 1);
        while (__hip_atomic_load(ctr, __ATOMIC_RELAXED, __HIP_MEMORY_SCOPE_AGENT) < NWG * (SEQL + 1))
            __builtin_amdgcn_s_sleep(1);
    }
    __syncthreads();
    __threadfence();

    if (blockIdx.x == 0 && tid < 64) {
        float v = (tid < NTAG) ? tags[tid] : -3.0e38f;
        float mx = v;
        #pragma unroll
        for (int m = 1; m < 64; m <<= 1) mx = fmaxf(mx, __shfl_xor(mx, m));
        float e = (tid < NTAG) ? __expf(v - mx) : 0.f;
        float se = e;
        #pragma unroll
        for (int m = 1; m < 64; m <<= 1) se += __shfl_xor(se, m);
        if (tid < NTAG) out[tid] = v - mx - __logf(se);
    }
}

// ---------------------------------------------------------------------------
extern "C" void kernel_launch(void* const* d_in, const int* in_sizes, int n_in,
                              void* d_out, int out_size, void* d_ws, size_t ws_size,
                              hipStream_t stream)
{
    const int*   seq  = (const int*)d_in[0];
    const float* emb  = (const float*)d_in[1];
    const float* Wih  = (const float*)d_in[2];
    const float* Whh  = (const float*)d_in[3];
    const float* bih  = (const float*)d_in[4];
    const float* bhh  = (const float*)d_in[5];
    const float* Wtag = (const float*)d_in[6];
    const float* btag = (const float*)d_in[7];
    float* out = (float*)d_out;

    float* xg   = (float*)d_ws;                    // 1024*8192 f32 = 32 MiB
    float* hbuf = xg + (size_t)SEQL * G4;          // 2*2048 f32 (double buffer)
    float* tags = hbuf + 2 * HID;                  // 50 f32
    int*   ctr  = (int*)(tags + 64);               // grid-barrier counter

    dim3 g1(G4 / 128, SEQL / 128);                 // (64, 8)
    gemm_xgates<<<g1, 256, 0, stream>>>(seq, emb, Wih, bih, bhh, xg, ctr);

    void* args[] = {(void*)&Whh, (void*)&xg, (void*)&Wtag, (void*)&btag,
                    (void*)&hbuf, (void*)&tags, (void*)&out, (void*)&ctr};
    hipLaunchCooperativeKernel((void*)lstm_recur, dim3(NWG), dim3(512),
                               args, 0, stream);
}

// Round 5
// 25094.608 us; speedup vs baseline: 2.8611x; 2.8611x over previous
//
#include <hip/hip_runtime.h>

#define SEQL 1024
#define EMB  2048
#define HID  2048
#define G4   8192   // 4*HID
#define NTAG 50
#define NWG  256

// ---------------------------------------------------------------------------
// Kernel 1: x_gates[t][n] = sum_k emb[seq[t]][k] * W_ih[n][k] + b_ih[n] + b_hh[n]
// f32 tiled GEMM, 128x128 tile, 256 threads, 8x8 micro-tile per thread.
// Also zeroes the 256 per-WG barrier flags for kernel 2.
// ---------------------------------------------------------------------------
__global__ __launch_bounds__(256) void gemm_xgates(
    const int* __restrict__ seq, const float* __restrict__ emb,
    const float* __restrict__ Wih, const float* __restrict__ bih,
    const float* __restrict__ bhh, float* __restrict__ xg, int* __restrict__ flags)
{
    if (blockIdx.x == 0 && blockIdx.y == 0) flags[threadIdx.x] = 0;  // 256 flags

    constexpr int BM = 128, BN = 128, BK = 32;
    __shared__ float As[BK][BM + 4];   // stored transposed: As[k][m]
    __shared__ float Bs[BK][BN + 4];
    __shared__ int   srow[BM];

    const int tid = threadIdx.x;
    const int bn = blockIdx.x, bm = blockIdx.y;

    if (tid < BM) srow[tid] = seq[bm * BM + tid];
    __syncthreads();

    const int tx = tid & 15, ty = tid >> 4;
    const int c4 = tid & 7;          // float4 column within BK
    const int r0 = tid >> 3;         // row 0..31 (4 batches of 32)

    float acc[8][8] = {};

    for (int k0 = 0; k0 < EMB; k0 += BK) {
        #pragma unroll
        for (int i = 0; i < 4; ++i) {
            const int r = r0 + 32 * i;
            float4 av = *(const float4*)(emb + (size_t)srow[r] * EMB + k0 + 4 * c4);
            As[4*c4+0][r] = av.x; As[4*c4+1][r] = av.y;
            As[4*c4+2][r] = av.z; As[4*c4+3][r] = av.w;
            float4 bv = *(const float4*)(Wih + (size_t)(bn * BN + r) * EMB + k0 + 4 * c4);
            Bs[4*c4+0][r] = bv.x; Bs[4*c4+1][r] = bv.y;
            Bs[4*c4+2][r] = bv.z; Bs[4*c4+3][r] = bv.w;
        }
        __syncthreads();
        #pragma unroll
        for (int kk = 0; kk < BK; ++kk) {
            float a[8], b[8];
            *(float4*)&a[0] = *(const float4*)&As[kk][8*ty];
            *(float4*)&a[4] = *(const float4*)&As[kk][8*ty+4];
            *(float4*)&b[0] = *(const float4*)&Bs[kk][8*tx];
            *(float4*)&b[4] = *(const float4*)&Bs[kk][8*tx+4];
            #pragma unroll
            for (int i = 0; i < 8; ++i)
                #pragma unroll
                for (int j = 0; j < 8; ++j)
                    acc[i][j] += a[i] * b[j];
        }
        __syncthreads();
    }

    const int gm = bm * BM + 8 * ty;
    const int gn = bn * BN + 8 * tx;
    float bb[8];
    #pragma unroll
    for (int j = 0; j < 8; ++j) bb[j] = bih[gn + j] + bhh[gn + j];
    #pragma unroll
    for (int i = 0; i < 8; ++i) {
        float4 o0, o1;
        o0.x = acc[i][0] + bb[0]; o0.y = acc[i][1] + bb[1];
        o0.z = acc[i][2] + bb[2]; o0.w = acc[i][3] + bb[3];
        o1.x = acc[i][4] + bb[4]; o1.y = acc[i][5] + bb[5];
        o1.z = acc[i][6] + bb[6]; o1.w = acc[i][7] + bb[7];
        *(float4*)(xg + (size_t)(gm + i) * G4 + gn)     = o0;
        *(float4*)(xg + (size_t)(gm + i) * G4 + gn + 4) = o1;
    }
}

// ---------------------------------------------------------------------------
// Kernel 2: persistent LSTM recurrence, 256 wgs x 512 threads (1 wg/CU).
// Weights in LDS as bf16 (128 KB/CU). NEW barrier: no atomic RMWs at all.
// Each WG STOREs its step number to its own flag (release, agent scope ->
// lands in L3; arrivals fully parallel). Readers poll the 256-flag array
// with relaxed agent dword loads (parallel, no serialization) +
// __syncthreads_and, then one acquire-only fence (waitcnt+inv, no L2
// writeback) and stage h (one float4/thread) into LDS.
// R2-R4 lesson: 256 atomicAdds on one line serialize at L3 (~270ns each)
// = the entire 70us/step.
// ---------------------------------------------------------------------------
__device__ __forceinline__ float sigm_(float x) { return 1.0f / (1.0f + __expf(-x)); }
__device__ __forceinline__ float tanh_(float x) {
    float e = __expf(2.0f * x);
    return (e - 1.0f) / (e + 1.0f);
}
__device__ __forceinline__ ushort f2bf_rne(float f) {
    unsigned u = __float_as_uint(f);
    unsigned r = (u + 0x7fffu + ((u >> 16) & 1u)) >> 16;   // round-nearest-even
    return (ushort)r;
}
__device__ __forceinline__ float bflo(unsigned u) { return __uint_as_float(u << 16); }
__device__ __forceinline__ float bfhi(unsigned u) { return __uint_as_float(u & 0xffff0000u); }

__global__ __launch_bounds__(512, 1) void lstm_recur(
    const float* __restrict__ Whh, const float* __restrict__ xg,
    const float* __restrict__ Wtag, const float* __restrict__ btag,
    float* __restrict__ hbuf, float* __restrict__ tags, float* __restrict__ out,
    int* __restrict__ flags)
{
    __shared__ ushort wbf[8][4][HID];   // 128 KB bf16 weights
    __shared__ float  shh[HID];         // 8 KB staged h
    __shared__ float  sh_red[8];

    const int tid = threadIdx.x;
    const int wv  = tid >> 6;              // wave 0..7
    const int l   = tid & 63;              // lane
    const int bid = blockIdx.x;
    const int j   = 8 * bid + wv;          // hidden unit owned by this wave

    // One-time: load W_hh rows, convert f32->bf16 (RNE), store LDS.
    // Layout: lane l covers k-chunks c = l + 64r (float4 granularity) ->
    // LDS strides 16B (h, f32) / 8B (w, bf16) per lane: conflict-free.
    #pragma unroll
    for (int q = 0; q < 4; ++q) {
        const float* wr = Whh + (size_t)(q * HID + j) * HID;
        #pragma unroll
        for (int i = 0; i < 8; ++i) {
            const int c = l + 64 * i;
            float4 v = *(const float4*)(wr + 4 * c);
            ushort4 b;
            b.x = f2bf_rne(v.x); b.y = f2bf_rne(v.y);
            b.z = f2bf_rne(v.z); b.w = f2bf_rne(v.w);
            *(ushort4*)&wbf[wv][q][4 * c] = b;
        }
    }

    // Poll helper: wait until all NWG flags >= target, then acquire-fence.
    auto pollflags = [&](int target) {
        for (;;) {
            int ok = 1;
            if (tid < NWG) {
                int f = __hip_atomic_load(flags + tid, __ATOMIC_RELAXED,
                                          __HIP_MEMORY_SCOPE_AGENT);
                ok = (f >= target);
            }
            if (__syncthreads_and(ok)) break;
            __builtin_amdgcn_s_sleep(1);
        }
        __builtin_amdgcn_fence(__ATOMIC_ACQUIRE, "agent");  // inv L1/L2, no wb
    };

    float cst = 0.0f;

    // Prefetch xg for t = 0.
    float xg0 = xg[j];
    float xg1 = xg[j + HID];
    float xg2 = xg[j + 2 * HID];
    float xg3 = xg[j + 3 * HID];

    for (int t = 0; t < SEQL; ++t) {
        float s0 = 0.f, s1 = 0.f, s2 = 0.f, s3 = 0.f;
        if (t > 0) {
            pollflags(t);                      // everyone's h_{t-1} is in L3
            // Stage h into LDS: one float4 per thread (post-inv normal loads).
            const float* hp = hbuf + ((t - 1) & 1) * HID;
            *(float4*)&shh[4 * tid] = *(const float4*)(hp + 4 * tid);
            __syncthreads();
            #pragma unroll
            for (int r = 0; r < 8; ++r) {
                const int kc = 4 * (l + 64 * r);
                float4 h4 = *(const float4*)&shh[kc];
                uint2 w0 = *(const uint2*)&wbf[wv][0][kc];
                uint2 w1 = *(const uint2*)&wbf[wv][1][kc];
                uint2 w2 = *(const uint2*)&wbf[wv][2][kc];
                uint2 w3 = *(const uint2*)&wbf[wv][3][kc];
                s0 += bflo(w0.x)*h4.x + bfhi(w0.x)*h4.y + bflo(w0.y)*h4.z + bfhi(w0.y)*h4.w;
                s1 += bflo(w1.x)*h4.x + bfhi(w1.x)*h4.y + bflo(w1.y)*h4.z + bfhi(w1.y)*h4.w;
                s2 += bflo(w2.x)*h4.x + bfhi(w2.x)*h4.y + bflo(w2.y)*h4.z + bfhi(w2.y)*h4.w;
                s3 += bflo(w3.x)*h4.x + bfhi(w3.x)*h4.y + bflo(w3.y)*h4.z + bfhi(w3.y)*h4.w;
            }
        } else {
            __syncthreads();                   // weights-in-LDS ready
        }
        #pragma unroll
        for (int m = 1; m < 64; m <<= 1) {
            s0 += __shfl_xor(s0, m);
            s1 += __shfl_xor(s1, m);
            s2 += __shfl_xor(s2, m);
            s3 += __shfl_xor(s3, m);
        }
        const float gi = sigm_(s0 + xg0);
        const float gf = sigm_(s1 + xg1);
        const float gg = tanh_(s2 + xg2);
        const float go = sigm_(s3 + xg3);
        cst = gf * cst + gi * gg;
        const float h = go * tanh_(cst);
        if (l == 0)
            __hip_atomic_store(hbuf + (t & 1) * HID + j, h,
                               __ATOMIC_RELAXED, __HIP_MEMORY_SCOPE_AGENT);

        // Prefetch next step's xg (values land in regs; immune to cache inv).
        const int tn = (t + 1 < SEQL) ? t + 1 : t;
        const size_t xb = (size_t)tn * G4 + j;
        xg0 = xg[xb];
        xg1 = xg[xb + HID];
        xg2 = xg[xb + 2 * HID];
        xg3 = xg[xb + 3 * HID];

        __syncthreads();                       // drains vmcnt: h stores at L3
        if (tid == 0)
            __hip_atomic_store(flags + bid, t + 1,
                               __ATOMIC_RELEASE, __HIP_MEMORY_SCOPE_AGENT);
    }

    // ---- wait for final h, then tag projection (wgs 0..49, one row each) ----
    pollflags(SEQL);
    const float* hfin = hbuf + HID;            // t=1023 wrote buffer 1
    if (bid < NTAG) {
        float4 w4 = *(const float4*)(Wtag + (size_t)bid * HID + 4 * tid);
        float4 h4 = *(const float4*)(hfin + 4 * tid);
        float part = w4.x*h4.x + w4.y*h4.y + w4.z*h4.z + w4.w*h4.w;
        #pragma unroll
        for (int m = 1; m < 64; m <<= 1) part += __shfl_xor(part, m);
        if (l == 0) sh_red[wv] = part;
    }
    __syncthreads();
    if (bid < NTAG && tid == 0) {
        float s = 0.f;
        #pragma unroll
        for (int i = 0; i < 8; ++i) s += sh_red[i];
        __hip_atomic_store(tags + bid, s + btag[bid],
                           __ATOMIC_RELAXED, __HIP_MEMORY_SCOPE_AGENT);
    }
    __syncthreads();
    if (tid == 0)
        __hip_atomic_store(flags + bid, SEQL + 1,
                           __ATOMIC_RELEASE, __HIP_MEMORY_SCOPE_AGENT);

    // ---- log_softmax on wg 0 ----
    if (bid == 0) {
        for (;;) {
            int ok = 1;
            if (tid < NTAG) {
                int f = __hip_atomic_load(flags + tid, __ATOMIC_RELAXED,
                                          __HIP_MEMORY_SCOPE_AGENT);
                ok = (f >= SEQL + 1);
            }
            if (__syncthreads_and(ok)) break;
            __builtin_amdgcn_s_sleep(1);
        }
        __builtin_amdgcn_fence(__ATOMIC_ACQUIRE, "agent");
        if (tid < 64) {
            float v = (tid < NTAG) ? tags[tid] : -3.0e38f;
            float mx = v;
            #pragma unroll
            for (int m = 1; m < 64; m <<= 1) mx = fmaxf(mx, __shfl_xor(mx, m));
            float e = (tid < NTAG) ? __expf(v - mx) : 0.f;
            float se = e;
            #pragma unroll
            for (int m = 1; m < 64; m <<= 1) se += __shfl_xor(se, m);
            if (tid < NTAG) out[tid] = v - mx - __logf(se);
        }
    }
}

// ---------------------------------------------------------------------------
extern "C" void kernel_launch(void* const* d_in, const int* in_sizes, int n_in,
                              void* d_out, int out_size, void* d_ws, size_t ws_size,
                              hipStream_t stream)
{
    const int*   seq  = (const int*)d_in[0];
    const float* emb  = (const float*)d_in[1];
    const float* Wih  = (const float*)d_in[2];
    const float* Whh  = (const float*)d_in[3];
    const float* bih  = (const float*)d_in[4];
    const float* bhh  = (const float*)d_in[5];
    const float* Wtag = (const float*)d_in[6];
    const float* btag = (const float*)d_in[7];
    float* out = (float*)d_out;

    float* xg    = (float*)d_ws;                   // 1024*8192 f32 = 32 MiB
    float* hbuf  = xg + (size_t)SEQL * G4;         // 2*2048 f32 (double buffer)
    float* tags  = hbuf + 2 * HID;                 // 50 f32 (padded to 64)
    int*   flags = (int*)(tags + 64);              // 256 per-WG flags

    dim3 g1(G4 / 128, SEQL / 128);                 // (64, 8)
    gemm_xgates<<<g1, 256, 0, stream>>>(seq, emb, Wih, bih, bhh, xg, flags);

    void* args[] = {(void*)&Whh, (void*)&xg, (void*)&Wtag, (void*)&btag,
                    (void*)&hbuf, (void*)&tags, (void*)&out, (void*)&flags};
    hipLaunchCooperativeKernel((void*)lstm_recur, dim3(NWG), dim3(512),
                               args, 0, stream);
}

// Round 6
// 7279.663 us; speedup vs baseline: 9.8629x; 3.4472x over previous
//
#include <hip/hip_runtime.h>

#define SEQL 1024
#define EMB  2048
#define HID  2048
#define G4   8192   // 4*HID
#define NTAG 50
#define NWG  256

// ---------------------------------------------------------------------------
// Kernel 1: x_gates[t][n] = sum_k emb[seq[t]][k] * W_ih[n][k] + b_ih[n] + b_hh[n]
// f32 tiled GEMM, 128x128 tile, 256 threads, 8x8 micro-tile per thread.
// Also zeroes the 256 per-WG barrier flags for kernel 2.
// ---------------------------------------------------------------------------
__global__ __launch_bounds__(256) void gemm_xgates(
    const int* __restrict__ seq, const float* __restrict__ emb,
    const float* __restrict__ Wih, const float* __restrict__ bih,
    const float* __restrict__ bhh, float* __restrict__ xg, int* __restrict__ flags)
{
    if (blockIdx.x == 0 && blockIdx.y == 0) flags[threadIdx.x] = 0;  // 256 flags

    constexpr int BM = 128, BN = 128, BK = 32;
    __shared__ float As[BK][BM + 4];   // stored transposed: As[k][m]
    __shared__ float Bs[BK][BN + 4];
    __shared__ int   srow[BM];

    const int tid = threadIdx.x;
    const int bn = blockIdx.x, bm = blockIdx.y;

    if (tid < BM) srow[tid] = seq[bm * BM + tid];
    __syncthreads();

    const int tx = tid & 15, ty = tid >> 4;
    const int c4 = tid & 7;          // float4 column within BK
    const int r0 = tid >> 3;         // row 0..31 (4 batches of 32)

    float acc[8][8] = {};

    for (int k0 = 0; k0 < EMB; k0 += BK) {
        #pragma unroll
        for (int i = 0; i < 4; ++i) {
            const int r = r0 + 32 * i;
            float4 av = *(const float4*)(emb + (size_t)srow[r] * EMB + k0 + 4 * c4);
            As[4*c4+0][r] = av.x; As[4*c4+1][r] = av.y;
            As[4*c4+2][r] = av.z; As[4*c4+3][r] = av.w;
            float4 bv = *(const float4*)(Wih + (size_t)(bn * BN + r) * EMB + k0 + 4 * c4);
            Bs[4*c4+0][r] = bv.x; Bs[4*c4+1][r] = bv.y;
            Bs[4*c4+2][r] = bv.z; Bs[4*c4+3][r] = bv.w;
        }
        __syncthreads();
        #pragma unroll
        for (int kk = 0; kk < BK; ++kk) {
            float a[8], b[8];
            *(float4*)&a[0] = *(const float4*)&As[kk][8*ty];
            *(float4*)&a[4] = *(const float4*)&As[kk][8*ty+4];
            *(float4*)&b[0] = *(const float4*)&Bs[kk][8*tx];
            *(float4*)&b[4] = *(const float4*)&Bs[kk][8*tx+4];
            #pragma unroll
            for (int i = 0; i < 8; ++i)
                #pragma unroll
                for (int j = 0; j < 8; ++j)
                    acc[i][j] += a[i] * b[j];
        }
        __syncthreads();
    }

    const int gm = bm * BM + 8 * ty;
    const int gn = bn * BN + 8 * tx;
    float bb[8];
    #pragma unroll
    for (int j = 0; j < 8; ++j) bb[j] = bih[gn + j] + bhh[gn + j];
    #pragma unroll
    for (int i = 0; i < 8; ++i) {
        float4 o0, o1;
        o0.x = acc[i][0] + bb[0]; o0.y = acc[i][1] + bb[1];
        o0.z = acc[i][2] + bb[2]; o0.w = acc[i][3] + bb[3];
        o1.x = acc[i][4] + bb[4]; o1.y = acc[i][5] + bb[5];
        o1.z = acc[i][6] + bb[6]; o1.w = acc[i][7] + bb[7];
        *(float4*)(xg + (size_t)(gm + i) * G4 + gn)     = o0;
        *(float4*)(xg + (size_t)(gm + i) * G4 + gn + 4) = o1;
    }
}

// ---------------------------------------------------------------------------
// L3-direct memory ops (sc0 sc1 = system scope: bypass L1+L2, hit the MALL).
// These make cross-XCD data flow WITHOUT any buffer_inv / buffer_wbl2 cache
// maintenance — R5's 23us/step was exactly those two ops (release store ->
// full L2 writeback scan; acquire fence -> full L1+L2 invalidate, per WG
// per step).
// ---------------------------------------------------------------------------
__device__ __forceinline__ float4 ld_f4_l3(const void* p) {
    float4 r;
    asm volatile("global_load_dwordx4 %0, %1, off sc0 sc1\n\ts_waitcnt vmcnt(0)"
                 : "=v"(r) : "v"(p) : "memory");
    return r;
}
__device__ __forceinline__ float ld_f32_l3(const void* p) {
    float r;
    asm volatile("global_load_dword %0, %1, off sc0 sc1\n\ts_waitcnt vmcnt(0)"
                 : "=v"(r) : "v"(p) : "memory");
    return r;
}
__device__ __forceinline__ int ld_i32_l3(const void* p) {
    int r;
    asm volatile("global_load_dword %0, %1, off sc0 sc1\n\ts_waitcnt vmcnt(0)"
                 : "=v"(r) : "v"(p) : "memory");
    return r;
}
__device__ __forceinline__ void st_f32_l3(void* p, float v) {
    asm volatile("global_store_dword %0, %1, off sc0 sc1"
                 :: "v"(p), "v"(v) : "memory");
}
// flag publish: drain this wave's outstanding stores first, then store flag.
__device__ __forceinline__ void st_flag_l3(void* p, int v) {
    asm volatile("s_waitcnt vmcnt(0)\n\tglobal_store_dword %0, %1, off sc0 sc1"
                 :: "v"(p), "v"(v) : "memory");
}

__device__ __forceinline__ float sigm_(float x) { return 1.0f / (1.0f + __expf(-x)); }
__device__ __forceinline__ float tanh_(float x) {
    float e = __expf(2.0f * x);
    return (e - 1.0f) / (e + 1.0f);
}
__device__ __forceinline__ ushort f2bf_rne(float f) {
    unsigned u = __float_as_uint(f);
    unsigned r = (u + 0x7fffu + ((u >> 16) & 1u)) >> 16;   // round-nearest-even
    return (ushort)r;
}
__device__ __forceinline__ float bflo(unsigned u) { return __uint_as_float(u << 16); }
__device__ __forceinline__ float bfhi(unsigned u) { return __uint_as_float(u & 0xffff0000u); }

// ---------------------------------------------------------------------------
// Kernel 2: persistent LSTM recurrence, 256 wgs x 512 threads (1 wg/CU).
// Weights in LDS as bf16 (128 KB/CU). Barrier: per-WG monotonic flag,
// published and polled with L3-direct (sc0 sc1) ops — no fences, no RMWs,
// no cache-wide maintenance anywhere in the step loop.
// ---------------------------------------------------------------------------
__global__ __launch_bounds__(512, 1) void lstm_recur(
    const float* __restrict__ Whh, const float* __restrict__ xg,
    const float* __restrict__ Wtag, const float* __restrict__ btag,
    float* __restrict__ hbuf, float* __restrict__ tags, float* __restrict__ out,
    int* __restrict__ flags)
{
    __shared__ ushort wbf[8][4][HID];   // 128 KB bf16 weights
    __shared__ float  shh[HID];         // 8 KB staged h
    __shared__ float  sh_red[8];

    const int tid = threadIdx.x;
    const int wv  = tid >> 6;              // wave 0..7
    const int l   = tid & 63;              // lane
    const int bid = blockIdx.x;
    const int j   = 8 * bid + wv;          // hidden unit owned by this wave

    // One-time: load W_hh rows, convert f32->bf16 (RNE), store LDS.
    #pragma unroll
    for (int q = 0; q < 4; ++q) {
        const float* wr = Whh + (size_t)(q * HID + j) * HID;
        #pragma unroll
        for (int i = 0; i < 8; ++i) {
            const int c = l + 64 * i;
            float4 v = *(const float4*)(wr + 4 * c);
            ushort4 b;
            b.x = f2bf_rne(v.x); b.y = f2bf_rne(v.y);
            b.z = f2bf_rne(v.z); b.w = f2bf_rne(v.w);
            *(ushort4*)&wbf[wv][q][4 * c] = b;
        }
    }

    // Poll: wait until all NWG flags >= target. L3-direct loads; no fence.
    auto pollflags = [&](int target) {
        for (;;) {
            int ok = 1;
            if (tid < NWG) ok = (ld_i32_l3(flags + tid) >= target);
            if (__syncthreads_and(ok)) break;
            __builtin_amdgcn_s_sleep(1);
        }
    };

    float cst = 0.0f;

    // Prefetch xg for t = 0 (xg is read-only: plain cached loads are fine).
    float xg0 = xg[j];
    float xg1 = xg[j + HID];
    float xg2 = xg[j + 2 * HID];
    float xg3 = xg[j + 3 * HID];

    for (int t = 0; t < SEQL; ++t) {
        float s0 = 0.f, s1 = 0.f, s2 = 0.f, s3 = 0.f;
        if (t > 0) {
            pollflags(t);                      // everyone's h_{t-1} is in L3
            // Stage h into LDS: one L3-direct float4 per thread.
            const float* hp = hbuf + ((t - 1) & 1) * HID;
            *(float4*)&shh[4 * tid] = ld_f4_l3(hp + 4 * tid);
            __syncthreads();
            #pragma unroll
            for (int r = 0; r < 8; ++r) {
                const int kc = 4 * (l + 64 * r);
                float4 h4 = *(const float4*)&shh[kc];
                uint2 w0 = *(const uint2*)&wbf[wv][0][kc];
                uint2 w1 = *(const uint2*)&wbf[wv][1][kc];
                uint2 w2 = *(const uint2*)&wbf[wv][2][kc];
                uint2 w3 = *(const uint2*)&wbf[wv][3][kc];
                s0 += bflo(w0.x)*h4.x + bfhi(w0.x)*h4.y + bflo(w0.y)*h4.z + bfhi(w0.y)*h4.w;
                s1 += bflo(w1.x)*h4.x + bfhi(w1.x)*h4.y + bflo(w1.y)*h4.z + bfhi(w1.y)*h4.w;
                s2 += bflo(w2.x)*h4.x + bfhi(w2.x)*h4.y + bflo(w2.y)*h4.z + bfhi(w2.y)*h4.w;
                s3 += bflo(w3.x)*h4.x + bfhi(w3.x)*h4.y + bflo(w3.y)*h4.z + bfhi(w3.y)*h4.w;
            }
        } else {
            __syncthreads();                   // weights-in-LDS ready
        }
        #pragma unroll
        for (int m = 1; m < 64; m <<= 1) {
            s0 += __shfl_xor(s0, m);
            s1 += __shfl_xor(s1, m);
            s2 += __shfl_xor(s2, m);
            s3 += __shfl_xor(s3, m);
        }
        const float gi = sigm_(s0 + xg0);
        const float gf = sigm_(s1 + xg1);
        const float gg = tanh_(s2 + xg2);
        const float go = sigm_(s3 + xg3);
        cst = gf * cst + gi * gg;
        const float h = go * tanh_(cst);
        if (l == 0) st_f32_l3(hbuf + (t & 1) * HID + j, h);

        // Prefetch next step's xg (L2 stays warm now — cheap hits).
        const int tn = (t + 1 < SEQL) ? t + 1 : t;
        const size_t xb = (size_t)tn * G4 + j;
        xg0 = xg[xb];
        xg1 = xg[xb + HID];
        xg2 = xg[xb + 2 * HID];
        xg3 = xg[xb + 3 * HID];

        __syncthreads();                       // all waves' h stores drained
        if (tid == 0) st_flag_l3(flags + bid, t + 1);
    }

    // ---- wait for final h, then tag projection (wgs 0..49, one row each) ----
    pollflags(SEQL);
    const float* hfin = hbuf + HID;            // t=1023 wrote buffer 1
    if (bid < NTAG) {
        float4 w4 = *(const float4*)(Wtag + (size_t)bid * HID + 4 * tid);
        float4 h4 = ld_f4_l3(hfin + 4 * tid);
        float part = w4.x*h4.x + w4.y*h4.y + w4.z*h4.z + w4.w*h4.w;
        #pragma unroll
        for (int m = 1; m < 64; m <<= 1) part += __shfl_xor(part, m);
        if (l == 0) sh_red[wv] = part;
    }
    __syncthreads();
    if (bid < NTAG && tid == 0) {
        float s = 0.f;
        #pragma unroll
        for (int i = 0; i < 8; ++i) s += sh_red[i];
        st_f32_l3(tags + bid, s + btag[bid]);
    }
    __syncthreads();
    if (tid == 0) st_flag_l3(flags + bid, SEQL + 1);

    // ---- log_softmax on wg 0 ----
    if (bid == 0) {
        for (;;) {
            int ok = 1;
            if (tid < NTAG) ok = (ld_i32_l3(flags + tid) >= SEQL + 1);
            if (__syncthreads_and(ok)) break;
            __builtin_amdgcn_s_sleep(1);
        }
        if (tid < 64) {
            float v = (tid < NTAG) ? ld_f32_l3(tags + tid) : -3.0e38f;
            float mx = v;
            #pragma unroll
            for (int m = 1; m < 64; m <<= 1) mx = fmaxf(mx, __shfl_xor(mx, m));
            float e = (tid < NTAG) ? __expf(v - mx) : 0.f;
            float se = e;
            #pragma unroll
            for (int m = 1; m < 64; m <<= 1) se += __shfl_xor(se, m);
            if (tid < NTAG) out[tid] = v - mx - __logf(se);
        }
    }
}

// ---------------------------------------------------------------------------
extern "C" void kernel_launch(void* const* d_in, const int* in_sizes, int n_in,
                              void* d_out, int out_size, void* d_ws, size_t ws_size,
                              hipStream_t stream)
{
    const int*   seq  = (const int*)d_in[0];
    const float* emb  = (const float*)d_in[1];
    const float* Wih  = (const float*)d_in[2];
    const float* Whh  = (const float*)d_in[3];
    const float* bih  = (const float*)d_in[4];
    const float* bhh  = (const float*)d_in[5];
    const float* Wtag = (const float*)d_in[6];
    const float* btag = (const float*)d_in[7];
    float* out = (float*)d_out;

    float* xg    = (float*)d_ws;                   // 1024*8192 f32 = 32 MiB
    float* hbuf  = xg + (size_t)SEQL * G4;         // 2*2048 f32 (double buffer)
    float* tags  = hbuf + 2 * HID;                 // 50 f32 (padded to 64)
    int*   flags = (int*)(tags + 64);              // 256 per-WG flags

    dim3 g1(G4 / 128, SEQL / 128);                 // (64, 8)
    gemm_xgates<<<g1, 256, 0, stream>>>(seq, emb, Wih, bih, bhh, xg, flags);

    void* args[] = {(void*)&Whh, (void*)&xg, (void*)&Wtag, (void*)&btag,
                    (void*)&hbuf, (void*)&tags, (void*)&out, (void*)&flags};
    hipLaunchCooperativeKernel((void*)lstm_recur, dim3(NWG), dim3(512),
                               args, 0, stream);
}

// Round 7
// 5257.425 us; speedup vs baseline: 13.6565x; 1.3846x over previous
//
#include <hip/hip_runtime.h>

#define SEQL 1024
#define EMB  2048
#define HID  2048
#define G4   8192   // 4*HID
#define NTAG 50
#define NWG  256

typedef _Float16 h2v __attribute__((ext_vector_type(2)));
typedef _Float16 h4v __attribute__((ext_vector_type(4)));

#if __has_builtin(__builtin_amdgcn_fdot2)
#define DOT2(a, b, c) __builtin_amdgcn_fdot2((a), (b), (c), false)
#else
#define DOT2(a, b, c) ((c) + (float)(a).x * (float)(b).x + (float)(a).y * (float)(b).y)
#endif
#define SH2(v, i, j) __builtin_shufflevector((v), (v), (i), (j))

// ---------------------------------------------------------------------------
// Kernel 1: x_gates[t][n] = emb[seq[t]] . W_ih[n] + b_ih[n] + b_hh[n]
// f32 tiled GEMM, 128x128 tile. Block (0,0) also zeroes the slot array
// (2 parities x 256 WGs x 16 dwords) used by kernel 2's barrier.
// ---------------------------------------------------------------------------
__global__ __launch_bounds__(256) void gemm_xgates(
    const int* __restrict__ seq, const float* __restrict__ emb,
    const float* __restrict__ Wih, const float* __restrict__ bih,
    const float* __restrict__ bhh, float* __restrict__ xg, int* __restrict__ slots)
{
    if (blockIdx.x == 0 && blockIdx.y == 0)
        for (int i = threadIdx.x; i < 2 * NWG * 16; i += 256) slots[i] = 0;

    constexpr int BM = 128, BN = 128, BK = 32;
    __shared__ float As[BK][BM + 4];
    __shared__ float Bs[BK][BN + 4];
    __shared__ int   srow[BM];

    const int tid = threadIdx.x;
    const int bn = blockIdx.x, bm = blockIdx.y;

    if (tid < BM) srow[tid] = seq[bm * BM + tid];
    __syncthreads();

    const int tx = tid & 15, ty = tid >> 4;
    const int c4 = tid & 7;
    const int r0 = tid >> 3;

    float acc[8][8] = {};

    for (int k0 = 0; k0 < EMB; k0 += BK) {
        #pragma unroll
        for (int i = 0; i < 4; ++i) {
            const int r = r0 + 32 * i;
            float4 av = *(const float4*)(emb + (size_t)srow[r] * EMB + k0 + 4 * c4);
            As[4*c4+0][r] = av.x; As[4*c4+1][r] = av.y;
            As[4*c4+2][r] = av.z; As[4*c4+3][r] = av.w;
            float4 bv = *(const float4*)(Wih + (size_t)(bn * BN + r) * EMB + k0 + 4 * c4);
            Bs[4*c4+0][r] = bv.x; Bs[4*c4+1][r] = bv.y;
            Bs[4*c4+2][r] = bv.z; Bs[4*c4+3][r] = bv.w;
        }
        __syncthreads();
        #pragma unroll
        for (int kk = 0; kk < BK; ++kk) {
            float a[8], b[8];
            *(float4*)&a[0] = *(const float4*)&As[kk][8*ty];
            *(float4*)&a[4] = *(const float4*)&As[kk][8*ty+4];
            *(float4*)&b[0] = *(const float4*)&Bs[kk][8*tx];
            *(float4*)&b[4] = *(const float4*)&Bs[kk][8*tx+4];
            #pragma unroll
            for (int i = 0; i < 8; ++i)
                #pragma unroll
                for (int j = 0; j < 8; ++j)
                    acc[i][j] += a[i] * b[j];
        }
        __syncthreads();
    }

    const int gm = bm * BM + 8 * ty;
    const int gn = bn * BN + 8 * tx;
    float bb[8];
    #pragma unroll
    for (int j = 0; j < 8; ++j) bb[j] = bih[gn + j] + bhh[gn + j];
    #pragma unroll
    for (int i = 0; i < 8; ++i) {
        float4 o0, o1;
        o0.x = acc[i][0] + bb[0]; o0.y = acc[i][1] + bb[1];
        o0.z = acc[i][2] + bb[2]; o0.w = acc[i][3] + bb[3];
        o1.x = acc[i][4] + bb[4]; o1.y = acc[i][5] + bb[5];
        o1.z = acc[i][6] + bb[6]; o1.w = acc[i][7] + bb[7];
        *(float4*)(xg + (size_t)(gm + i) * G4 + gn)     = o0;
        *(float4*)(xg + (size_t)(gm + i) * G4 + gn + 4) = o1;
    }
}

// ---------------------------------------------------------------------------
// L3-direct (sc0 sc1) helpers — cross-XCD data at the coherence point, zero
// cache maintenance (no buffer_inv / buffer_wbl2).
// ---------------------------------------------------------------------------
__device__ __forceinline__ uint4 ld_u4_l3_nw(const void* p) {   // no wait
    uint4 r;
    asm volatile("global_load_dwordx4 %0, %1, off sc0 sc1"
                 : "=v"(r) : "v"(p) : "memory");
    return r;
}
__device__ __forceinline__ int ld_i32_l3(const void* p) {
    int r;
    asm volatile("global_load_dword %0, %1, off sc0 sc1\n\ts_waitcnt vmcnt(0)"
                 : "=v"(r) : "v"(p) : "memory");
    return r;
}
__device__ __forceinline__ float ld_f32_l3(const void* p) {
    float r;
    asm volatile("global_load_dword %0, %1, off sc0 sc1\n\ts_waitcnt vmcnt(0)"
                 : "=v"(r) : "v"(p) : "memory");
    return r;
}
__device__ __forceinline__ void st_u16_l3(void* p, ushort v) {
    asm volatile("global_store_short %0, %1, off sc0 sc1"
                 :: "v"(p), "v"(v) : "memory");
}
__device__ __forceinline__ void st_u32_l3(void* p, int v) {
    asm volatile("global_store_dword %0, %1, off sc0 sc1"
                 :: "v"(p), "v"(v) : "memory");
}
__device__ __forceinline__ void st_f32_l3(void* p, float v) {
    asm volatile("global_store_dword %0, %1, off sc0 sc1"
                 :: "v"(p), "v"(v) : "memory");
}
__device__ __forceinline__ void wait_vm0() {
    asm volatile("s_waitcnt vmcnt(0)" ::: "memory");
}

__device__ __forceinline__ float sigm_(float x) { return 1.0f / (1.0f + __expf(-x)); }
__device__ __forceinline__ float tanh_(float x) {
    float e = __expf(2.0f * x);
    return (e - 1.0f) / (e + 1.0f);
}

// ---------------------------------------------------------------------------
// Kernel 2: persistent LSTM recurrence, 256 wgs x 512 threads (1 wg/CU).
// Weights in LDS as f16 (128 KB/CU), inner product via v_dot2_f32_f16.
// Cross-WG exchange: per-WG 64B slot = {8 x f16 h, flag dword} per parity.
// Producer: 8 waves store h f16 -> ALL waves s_waitcnt vmcnt(0) ->
// __syncthreads -> tid0 stores flag (race-free). Consumer: poll flag; in the
// SAME iteration the flag is seen, issue the h dwordx4 (provably fresh:
// issued after flag load completed), overlap with barrier convergence.
// xg prefetch issued ~1us before the producer drain so the flag publish is
// never delayed by it (R6 flaw).
// ---------------------------------------------------------------------------
__global__ __launch_bounds__(512, 1) void lstm_recur(
    const float* __restrict__ Whh, const float* __restrict__ xg,
    const float* __restrict__ Wtag, const float* __restrict__ btag,
    unsigned int* __restrict__ slots, float* __restrict__ tags,
    float* __restrict__ out)
{
    __shared__ __align__(16) ushort wf16[8][4][HID];  // 128 KB f16 weights
    __shared__ __align__(16) ushort shh16[HID];       // 4 KB staged h (f16)
    __shared__ float sh_red[8];

    const int tid = threadIdx.x;
    const int wv  = tid >> 6;              // wave 0..7
    const int l   = tid & 63;              // lane
    const int bid = blockIdx.x;
    const int j   = 8 * bid + wv;          // hidden unit owned by this wave

    // One-time: W_hh rows -> f16 -> LDS. Lane l owns 8-elem chunks c8=l+64i.
    #pragma unroll
    for (int q = 0; q < 4; ++q) {
        const float* wr = Whh + (size_t)(q * HID + j) * HID;
        #pragma unroll
        for (int i = 0; i < 4; ++i) {
            const int c8 = l + 64 * i;
            float4 va = *(const float4*)(wr + 8 * c8);
            float4 vb = *(const float4*)(wr + 8 * c8 + 4);
            h4v wa = {(_Float16)va.x, (_Float16)va.y, (_Float16)va.z, (_Float16)va.w};
            h4v wb = {(_Float16)vb.x, (_Float16)vb.y, (_Float16)vb.z, (_Float16)vb.w};
            *(h4v*)&wf16[wv][q][8 * c8]     = wa;
            *(h4v*)&wf16[wv][q][8 * c8 + 4] = wb;
        }
    }

    // Poll all NWG slot flags >= target (parity buffer), fetch h in the same
    // iteration the flag is observed, stage into LDS.
    auto poll_stage = [&](int target, int parity) {
        unsigned int* pslot = slots + 16 * (parity * NWG + tid);
        uint4 hd = {0, 0, 0, 0};
        int got = 0;
        for (;;) {
            int ok = 1;
            if (tid < NWG) {
                int f = ld_i32_l3(pslot + 4);
                ok = (f >= target);
                if (ok && !got) { hd = ld_u4_l3_nw(pslot); got = 1; }
            }
            if (__syncthreads_and(ok)) break;
            __builtin_amdgcn_s_sleep(1);
        }
        wait_vm0();
        if (tid < NWG) *(uint4*)&shh16[8 * tid] = hd;
        __syncthreads();
    };

    float cst = 0.0f;
    float xg0 = xg[j], xg1 = xg[j + HID], xg2 = xg[j + 2 * HID], xg3 = xg[j + 3 * HID];

    for (int t = 0; t < SEQL; ++t) {
        if (t > 0) poll_stage(t, (t - 1) & 1);
        else       __syncthreads();            // weights-in-LDS ready

        // Prefetch next step's xg NOW — completes during the dot compute,
        // so the producer drain below never stalls on it.
        const int tn = (t + 1 < SEQL) ? t + 1 : t;
        const size_t xb = (size_t)tn * G4 + j;
        const float nx0 = xg[xb];
        const float nx1 = xg[xb + HID];
        const float nx2 = xg[xb + 2 * HID];
        const float nx3 = xg[xb + 3 * HID];

        float s0 = 0.f, s1 = 0.f, s2 = 0.f, s3 = 0.f;
        if (t > 0) {
            #pragma unroll
            for (int r = 0; r < 4; ++r) {
                const int kc = 8 * (l + 64 * r);
                h4v ha = *(const h4v*)&shh16[kc];
                h4v hb = *(const h4v*)&shh16[kc + 4];
                h2v h0 = SH2(ha, 0, 1), h1 = SH2(ha, 2, 3);
                h2v h2 = SH2(hb, 0, 1), h3 = SH2(hb, 2, 3);
                h4v w;
                w = *(const h4v*)&wf16[wv][0][kc];
                s0 = DOT2(SH2(w,0,1), h0, s0); s0 = DOT2(SH2(w,2,3), h1, s0);
                w = *(const h4v*)&wf16[wv][0][kc + 4];
                s0 = DOT2(SH2(w,0,1), h2, s0); s0 = DOT2(SH2(w,2,3), h3, s0);
                w = *(const h4v*)&wf16[wv][1][kc];
                s1 = DOT2(SH2(w,0,1), h0, s1); s1 = DOT2(SH2(w,2,3), h1, s1);
                w = *(const h4v*)&wf16[wv][1][kc + 4];
                s1 = DOT2(SH2(w,0,1), h2, s1); s1 = DOT2(SH2(w,2,3), h3, s1);
                w = *(const h4v*)&wf16[wv][2][kc];
                s2 = DOT2(SH2(w,0,1), h0, s2); s2 = DOT2(SH2(w,2,3), h1, s2);
                w = *(const h4v*)&wf16[wv][2][kc + 4];
                s2 = DOT2(SH2(w,0,1), h2, s2); s2 = DOT2(SH2(w,2,3), h3, s2);
                w = *(const h4v*)&wf16[wv][3][kc];
                s3 = DOT2(SH2(w,0,1), h0, s3); s3 = DOT2(SH2(w,2,3), h1, s3);
                w = *(const h4v*)&wf16[wv][3][kc + 4];
                s3 = DOT2(SH2(w,0,1), h2, s3); s3 = DOT2(SH2(w,2,3), h3, s3);
            }
        }
        #pragma unroll
        for (int m = 1; m < 64; m <<= 1) {
            s0 += __shfl_xor(s0, m);
            s1 += __shfl_xor(s1, m);
            s2 += __shfl_xor(s2, m);
            s3 += __shfl_xor(s3, m);
        }
        const float gi = sigm_(s0 + xg0);
        const float gf = sigm_(s1 + xg1);
        const float gg = tanh_(s2 + xg2);
        const float go = sigm_(s3 + xg3);
        cst = gf * cst + gi * gg;
        const float h = go * tanh_(cst);

        unsigned int* myslot = slots + 16 * ((t & 1) * NWG + bid);
        if (l == 0) {
            _Float16 hf = (_Float16)h;
            st_u16_l3((char*)myslot + 2 * wv, __builtin_bit_cast(ushort, hf));
        }
        wait_vm0();                            // ALL waves drain h store (+nx)
        __syncthreads();
        if (tid == 0) st_u32_l3(myslot + 4, t + 1);

        xg0 = nx0; xg1 = nx1; xg2 = nx2; xg3 = nx3;
    }

    // ---- final h, tag projection (wgs 0..49, one tag row each) ----
    poll_stage(SEQL, (SEQL - 1) & 1);          // stage h_1023 (f16) into LDS
    if (bid < NTAG) {
        h4v hv4 = *(const h4v*)&shh16[4 * tid];
        float4 w4 = *(const float4*)(Wtag + (size_t)bid * HID + 4 * tid);
        float part = w4.x * (float)hv4.x + w4.y * (float)hv4.y
                   + w4.z * (float)hv4.z + w4.w * (float)hv4.w;
        #pragma unroll
        for (int m = 1; m < 64; m <<= 1) part += __shfl_xor(part, m);
        if (l == 0) sh_red[wv] = part;
    }
    __syncthreads();
    if (bid < NTAG && tid == 0) {
        float s = 0.f;
        #pragma unroll
        for (int i = 0; i < 8; ++i) s += sh_red[i];
        st_f32_l3(tags + bid, s + btag[bid]);
    }
    wait_vm0();
    __syncthreads();
    if (tid == 0) st_u32_l3(slots + 16 * bid + 4, SEQL + 1);   // parity-0 flag

    // ---- log_softmax on wg 0 ----
    if (bid == 0) {
        for (;;) {
            int ok = 1;
            if (tid < NTAG) ok = (ld_i32_l3(slots + 16 * tid + 4) >= SEQL + 1);
            if (__syncthreads_and(ok)) break;
            __builtin_amdgcn_s_sleep(1);
        }
        if (tid < 64) {
            float v = (tid < NTAG) ? ld_f32_l3(tags + tid) : -3.0e38f;
            float mx = v;
            #pragma unroll
            for (int m = 1; m < 64; m <<= 1) mx = fmaxf(mx, __shfl_xor(mx, m));
            float e = (tid < NTAG) ? __expf(v - mx) : 0.f;
            float se = e;
            #pragma unroll
            for (int m = 1; m < 64; m <<= 1) se += __shfl_xor(se, m);
            if (tid < NTAG) out[tid] = v - mx - __logf(se);
        }
    }
}

// ---------------------------------------------------------------------------
extern "C" void kernel_launch(void* const* d_in, const int* in_sizes, int n_in,
                              void* d_out, int out_size, void* d_ws, size_t ws_size,
                              hipStream_t stream)
{
    const int*   seq  = (const int*)d_in[0];
    const float* emb  = (const float*)d_in[1];
    const float* Wih  = (const float*)d_in[2];
    const float* Whh  = (const float*)d_in[3];
    const float* bih  = (const float*)d_in[4];
    const float* bhh  = (const float*)d_in[5];
    const float* Wtag = (const float*)d_in[6];
    const float* btag = (const float*)d_in[7];
    float* out = (float*)d_out;

    float* xg    = (float*)d_ws;                   // 1024*8192 f32 = 32 MiB
    unsigned int* slots = (unsigned int*)(xg + (size_t)SEQL * G4);  // 2*256*16 u32
    float* tags  = (float*)(slots + 2 * NWG * 16); // 50 f32 (pad 64)

    dim3 g1(G4 / 128, SEQL / 128);                 // (64, 8)
    gemm_xgates<<<g1, 256, 0, stream>>>(seq, emb, Wih, bih, bhh, xg, (int*)slots);

    void* args[] = {(void*)&Whh, (void*)&xg, (void*)&Wtag, (void*)&btag,
                    (void*)&slots, (void*)&tags, (void*)&out};
    hipLaunchCooperativeKernel((void*)lstm_recur, dim3(NWG), dim3(512),
                               args, 0, stream);
}

// Round 8
// 5155.081 us; speedup vs baseline: 13.9277x; 1.0199x over previous
//
#include <hip/hip_runtime.h>

#define SEQL 1024
#define EMB  2048
#define HID  2048
#define G4   8192   // 4*HID
#define NTAG 50
#define NWG  256

typedef _Float16 h2v __attribute__((ext_vector_type(2)));
typedef _Float16 h4v __attribute__((ext_vector_type(4)));

#if __has_builtin(__builtin_amdgcn_fdot2)
#define DOT2(a, b, c) __builtin_amdgcn_fdot2((a), (b), (c), false)
#else
#define DOT2(a, b, c) ((c) + (float)(a).x * (float)(b).x + (float)(a).y * (float)(b).y)
#endif
#define SH2(v, i, j) __builtin_shufflevector((v), (v), (i), (j))

// ---------------------------------------------------------------------------
// Kernel 1: x_gates[t][n] = emb[seq[t]] . W_ih[n] + b_ih[n] + b_hh[n]
// f32 tiled GEMM, 128x128 tile. Block (0,0) also zeroes kernel 2's hslot
// stamps (2 parities x 2048 dwords) and the final-phase flags (256 ints).
// Zeroing here (before lstm_recur on the same stream) also resets state
// between graph replays.
// ---------------------------------------------------------------------------
__global__ __launch_bounds__(256) void gemm_xgates(
    const int* __restrict__ seq, const float* __restrict__ emb,
    const float* __restrict__ Wih, const float* __restrict__ bih,
    const float* __restrict__ bhh, float* __restrict__ xg,
    unsigned int* __restrict__ hslot, int* __restrict__ flags)
{
    if (blockIdx.x == 0 && blockIdx.y == 0) {
        for (int i = threadIdx.x; i < 2 * HID; i += 256) hslot[i] = 0;
        if (threadIdx.x < NWG) flags[threadIdx.x] = 0;
    }

    constexpr int BM = 128, BN = 128, BK = 32;
    __shared__ float As[BK][BM + 4];
    __shared__ float Bs[BK][BN + 4];
    __shared__ int   srow[BM];

    const int tid = threadIdx.x;
    const int bn = blockIdx.x, bm = blockIdx.y;

    if (tid < BM) srow[tid] = seq[bm * BM + tid];
    __syncthreads();

    const int tx = tid & 15, ty = tid >> 4;
    const int c4 = tid & 7;
    const int r0 = tid >> 3;

    float acc[8][8] = {};

    for (int k0 = 0; k0 < EMB; k0 += BK) {
        #pragma unroll
        for (int i = 0; i < 4; ++i) {
            const int r = r0 + 32 * i;
            float4 av = *(const float4*)(emb + (size_t)srow[r] * EMB + k0 + 4 * c4);
            As[4*c4+0][r] = av.x; As[4*c4+1][r] = av.y;
            As[4*c4+2][r] = av.z; As[4*c4+3][r] = av.w;
            float4 bv = *(const float4*)(Wih + (size_t)(bn * BN + r) * EMB + k0 + 4 * c4);
            Bs[4*c4+0][r] = bv.x; Bs[4*c4+1][r] = bv.y;
            Bs[4*c4+2][r] = bv.z; Bs[4*c4+3][r] = bv.w;
        }
        __syncthreads();
        #pragma unroll
        for (int kk = 0; kk < BK; ++kk) {
            float a[8], b[8];
            *(float4*)&a[0] = *(const float4*)&As[kk][8*ty];
            *(float4*)&a[4] = *(const float4*)&As[kk][8*ty+4];
            *(float4*)&b[0] = *(const float4*)&Bs[kk][8*tx];
            *(float4*)&b[4] = *(const float4*)&Bs[kk][8*tx+4];
            #pragma unroll
            for (int i = 0; i < 8; ++i)
                #pragma unroll
                for (int j = 0; j < 8; ++j)
                    acc[i][j] += a[i] * b[j];
        }
        __syncthreads();
    }

    const int gm = bm * BM + 8 * ty;
    const int gn = bn * BN + 8 * tx;
    float bb[8];
    #pragma unroll
    for (int j = 0; j < 8; ++j) bb[j] = bih[gn + j] + bhh[gn + j];
    #pragma unroll
    for (int i = 0; i < 8; ++i) {
        float4 o0, o1;
        o0.x = acc[i][0] + bb[0]; o0.y = acc[i][1] + bb[1];
        o0.z = acc[i][2] + bb[2]; o0.w = acc[i][3] + bb[3];
        o1.x = acc[i][4] + bb[4]; o1.y = acc[i][5] + bb[5];
        o1.z = acc[i][6] + bb[6]; o1.w = acc[i][7] + bb[7];
        *(float4*)(xg + (size_t)(gm + i) * G4 + gn)     = o0;
        *(float4*)(xg + (size_t)(gm + i) * G4 + gn + 4) = o1;
    }
}

// ---------------------------------------------------------------------------
// L3-direct (sc0 sc1) helpers — data at the coherence point, zero cache
// maintenance.
// ---------------------------------------------------------------------------
__device__ __forceinline__ uint4 ld_u4_l3(const void* p) {
    uint4 r;
    asm volatile("global_load_dwordx4 %0, %1, off sc0 sc1\n\ts_waitcnt vmcnt(0)"
                 : "=v"(r) : "v"(p) : "memory");
    return r;
}
__device__ __forceinline__ int ld_i32_l3(const void* p) {
    int r;
    asm volatile("global_load_dword %0, %1, off sc0 sc1\n\ts_waitcnt vmcnt(0)"
                 : "=v"(r) : "v"(p) : "memory");
    return r;
}
__device__ __forceinline__ float ld_f32_l3(const void* p) {
    float r;
    asm volatile("global_load_dword %0, %1, off sc0 sc1\n\ts_waitcnt vmcnt(0)"
                 : "=v"(r) : "v"(p) : "memory");
    return r;
}
__device__ __forceinline__ void st_u32_l3(void* p, unsigned int v) {
    asm volatile("global_store_dword %0, %1, off sc0 sc1"
                 :: "v"(p), "v"(v) : "memory");
}
__device__ __forceinline__ void st_f32_l3(void* p, float v) {
    asm volatile("global_store_dword %0, %1, off sc0 sc1"
                 :: "v"(p), "v"(v) : "memory");
}
__device__ __forceinline__ void wait_vm0() {
    asm volatile("s_waitcnt vmcnt(0)" ::: "memory");
}

__device__ __forceinline__ float sigm_(float x) { return 1.0f / (1.0f + __expf(-x)); }
__device__ __forceinline__ float tanh_(float x) {
    float e = __expf(2.0f * x);
    return (e - 1.0f) / (e + 1.0f);
}

// ---------------------------------------------------------------------------
// Kernel 2: persistent LSTM recurrence, 256 wgs x 512 threads (1 wg/CU).
// Weights in LDS as f16, inner product via v_dot2_f32_f16.
// Cross-WG exchange: ONE dword per hidden unit = {stamp:u16=t+1, h:f16}.
// Producer (wave lane0) stores it directly — no gather, no drain, no flag.
// Consumers: 512 threads each poll 4 contiguous units with one dwordx4;
// stamp match => h already in regs (same dword — no data/flag tear).
// Double-buffered by step parity; during a poll for stamp T, slot values
// are provably in {T-2, T}, so '==' detection is exact.
// ---------------------------------------------------------------------------
__global__ __launch_bounds__(512, 1) void lstm_recur(
    const float* __restrict__ Whh, const float* __restrict__ xg,
    const float* __restrict__ Wtag, const float* __restrict__ btag,
    unsigned int* __restrict__ hslot, float* __restrict__ tags,
    float* __restrict__ out, int* __restrict__ flags)
{
    __shared__ __align__(16) ushort wf16[8][4][HID];  // 128 KB f16 weights
    __shared__ __align__(16) ushort shh16[HID];       // 4 KB staged h (f16)
    __shared__ float sh_red[8];

    const int tid = threadIdx.x;
    const int wv  = tid >> 6;              // wave 0..7
    const int l   = tid & 63;              // lane
    const int bid = blockIdx.x;
    const int j   = 8 * bid + wv;          // hidden unit owned by this wave

    // One-time: W_hh rows -> f16 -> LDS. Lane l owns 8-elem chunks c8=l+64i.
    #pragma unroll
    for (int q = 0; q < 4; ++q) {
        const float* wr = Whh + (size_t)(q * HID + j) * HID;
        #pragma unroll
        for (int i = 0; i < 4; ++i) {
            const int c8 = l + 64 * i;
            float4 va = *(const float4*)(wr + 8 * c8);
            float4 vb = *(const float4*)(wr + 8 * c8 + 4);
            h4v wa = {(_Float16)va.x, (_Float16)va.y, (_Float16)va.z, (_Float16)va.w};
            h4v wb = {(_Float16)vb.x, (_Float16)vb.y, (_Float16)vb.z, (_Float16)vb.w};
            *(h4v*)&wf16[wv][q][8 * c8]     = wa;
            *(h4v*)&wf16[wv][q][8 * c8 + 4] = wb;
        }
    }

    // Poll 4 units/thread until all stamps == target; stage h into LDS.
    auto poll_stage = [&](int target, int parity) {
        const unsigned int* base = hslot + parity * HID + 4 * tid;
        const ushort tgt = (ushort)target;
        uint4 d;
        for (;;) {
            d = ld_u4_l3(base);
            int ok = ((ushort)(d.x >> 16) == tgt) & ((ushort)(d.y >> 16) == tgt)
                   & ((ushort)(d.z >> 16) == tgt) & ((ushort)(d.w >> 16) == tgt);
            if (__syncthreads_and(ok)) break;
            __builtin_amdgcn_s_sleep(1);
        }
        ushort4 hh = {(ushort)d.x, (ushort)d.y, (ushort)d.z, (ushort)d.w};
        *(ushort4*)&shh16[4 * tid] = hh;       // 8B ds_write, contiguous
        __syncthreads();
    };

    float cst = 0.0f;
    float xg0 = xg[j], xg1 = xg[j + HID], xg2 = xg[j + 2 * HID], xg3 = xg[j + 3 * HID];

    for (int t = 0; t < SEQL; ++t) {
        if (t > 0) poll_stage(t, (t - 1) & 1);
        else       __syncthreads();            // weights-in-LDS ready

        // Prefetch next step's xg; completes during the dot compute.
        const int tn = (t + 1 < SEQL) ? t + 1 : t;
        const size_t xb = (size_t)tn * G4 + j;
        const float nx0 = xg[xb];
        const float nx1 = xg[xb + HID];
        const float nx2 = xg[xb + 2 * HID];
        const float nx3 = xg[xb + 3 * HID];

        float s0 = 0.f, s1 = 0.f, s2 = 0.f, s3 = 0.f;
        if (t > 0) {
            #pragma unroll
            for (int r = 0; r < 4; ++r) {
                const int kc = 8 * (l + 64 * r);
                h4v ha = *(const h4v*)&shh16[kc];
                h4v hb = *(const h4v*)&shh16[kc + 4];
                h2v h0 = SH2(ha, 0, 1), h1 = SH2(ha, 2, 3);
                h2v h2 = SH2(hb, 0, 1), h3 = SH2(hb, 2, 3);
                h4v w;
                w = *(const h4v*)&wf16[wv][0][kc];
                s0 = DOT2(SH2(w,0,1), h0, s0); s0 = DOT2(SH2(w,2,3), h1, s0);
                w = *(const h4v*)&wf16[wv][0][kc + 4];
                s0 = DOT2(SH2(w,0,1), h2, s0); s0 = DOT2(SH2(w,2,3), h3, s0);
                w = *(const h4v*)&wf16[wv][1][kc];
                s1 = DOT2(SH2(w,0,1), h0, s1); s1 = DOT2(SH2(w,2,3), h1, s1);
                w = *(const h4v*)&wf16[wv][1][kc + 4];
                s1 = DOT2(SH2(w,0,1), h2, s1); s1 = DOT2(SH2(w,2,3), h3, s1);
                w = *(const h4v*)&wf16[wv][2][kc];
                s2 = DOT2(SH2(w,0,1), h0, s2); s2 = DOT2(SH2(w,2,3), h1, s2);
                w = *(const h4v*)&wf16[wv][2][kc + 4];
                s2 = DOT2(SH2(w,0,1), h2, s2); s2 = DOT2(SH2(w,2,3), h3, s2);
                w = *(const h4v*)&wf16[wv][3][kc];
                s3 = DOT2(SH2(w,0,1), h0, s3); s3 = DOT2(SH2(w,2,3), h1, s3);
                w = *(const h4v*)&wf16[wv][3][kc + 4];
                s3 = DOT2(SH2(w,0,1), h2, s3); s3 = DOT2(SH2(w,2,3), h3, s3);
            }
        }
        #pragma unroll
        for (int m = 1; m < 64; m <<= 1) {
            s0 += __shfl_xor(s0, m);
            s1 += __shfl_xor(s1, m);
            s2 += __shfl_xor(s2, m);
            s3 += __shfl_xor(s3, m);
        }
        const float gi = sigm_(s0 + xg0);
        const float gf = sigm_(s1 + xg1);
        const float gg = tanh_(s2 + xg2);
        const float go = sigm_(s3 + xg3);
        cst = gf * cst + gi * gg;
        const float h = go * tanh_(cst);

        if (l == 0) {
            _Float16 hf = (_Float16)h;
            unsigned int d = ((unsigned int)(ushort)(t + 1) << 16)
                           | (unsigned int)__builtin_bit_cast(ushort, hf);
            st_u32_l3(hslot + (t & 1) * HID + j, d);   // data+stamp, one store
        }

        xg0 = nx0; xg1 = nx1; xg2 = nx2; xg3 = nx3;
    }

    // ---- final h, tag projection (wgs 0..49, one tag row each) ----
    poll_stage(SEQL, (SEQL - 1) & 1);          // stage h_1023 (f16) into LDS
    if (bid < NTAG) {
        h4v hv4 = *(const h4v*)&shh16[4 * tid];
        float4 w4 = *(const float4*)(Wtag + (size_t)bid * HID + 4 * tid);
        float part = w4.x * (float)hv4.x + w4.y * (float)hv4.y
                   + w4.z * (float)hv4.z + w4.w * (float)hv4.w;
        #pragma unroll
        for (int m = 1; m < 64; m <<= 1) part += __shfl_xor(part, m);
        if (l == 0) sh_red[wv] = part;
    }
    __syncthreads();
    if (bid < NTAG && tid == 0) {
        float s = 0.f;
        #pragma unroll
        for (int i = 0; i < 8; ++i) s += sh_red[i];
        st_f32_l3(tags + bid, s + btag[bid]);
    }
    wait_vm0();
    __syncthreads();
    if (tid == 0) st_u32_l3((unsigned int*)(flags + bid), 1u);

    // ---- log_softmax on wg 0 ----
    if (bid == 0) {
        for (;;) {
            int ok = 1;
            if (tid < NTAG) ok = (ld_i32_l3(flags + tid) >= 1);
            if (__syncthreads_and(ok)) break;
            __builtin_amdgcn_s_sleep(1);
        }
        if (tid < 64) {
            float v = (tid < NTAG) ? ld_f32_l3(tags + tid) : -3.0e38f;
            float mx = v;
            #pragma unroll
            for (int m = 1; m < 64; m <<= 1) mx = fmaxf(mx, __shfl_xor(mx, m));
            float e = (tid < NTAG) ? __expf(v - mx) : 0.f;
            float se = e;
            #pragma unroll
            for (int m = 1; m < 64; m <<= 1) se += __shfl_xor(se, m);
            if (tid < NTAG) out[tid] = v - mx - __logf(se);
        }
    }
}

// ---------------------------------------------------------------------------
extern "C" void kernel_launch(void* const* d_in, const int* in_sizes, int n_in,
                              void* d_out, int out_size, void* d_ws, size_t ws_size,
                              hipStream_t stream)
{
    const int*   seq  = (const int*)d_in[0];
    const float* emb  = (const float*)d_in[1];
    const float* Wih  = (const float*)d_in[2];
    const float* Whh  = (const float*)d_in[3];
    const float* bih  = (const float*)d_in[4];
    const float* bhh  = (const float*)d_in[5];
    const float* Wtag = (const float*)d_in[6];
    const float* btag = (const float*)d_in[7];
    float* out = (float*)d_out;

    float* xg = (float*)d_ws;                              // 32 MiB
    unsigned int* hslot = (unsigned int*)(xg + (size_t)SEQL * G4);  // 2*2048 u32
    float* tags  = (float*)(hslot + 2 * HID);              // 50 f32 (pad 64)
    int*   flags = (int*)(tags + 64);                      // 256 ints

    dim3 g1(G4 / 128, SEQL / 128);                         // (64, 8)
    gemm_xgates<<<g1, 256, 0, stream>>>(seq, emb, Wih, bih, bhh, xg, hslot, flags);

    void* args[] = {(void*)&Whh, (void*)&xg, (void*)&Wtag, (void*)&btag,
                    (void*)&hslot, (void*)&tags, (void*)&out, (void*)&flags};
    hipLaunchCooperativeKernel((void*)lstm_recur, dim3(NWG), dim3(512),
                               args, 0, stream);
}

// Round 9
// 3367.953 us; speedup vs baseline: 21.3181x; 1.5306x over previous
//
#include <hip/hip_runtime.h>

#define SEQL 1024
#define EMB  2048
#define HID  2048
#define G4   8192   // 4*HID
#define NTAG 50
#define NWG  256

typedef _Float16 h2v __attribute__((ext_vector_type(2)));
typedef _Float16 h4v __attribute__((ext_vector_type(4)));

#if __has_builtin(__builtin_amdgcn_fdot2)
#define DOT2(a, b, c) __builtin_amdgcn_fdot2((a), (b), (c), false)
#else
#define DOT2(a, b, c) ((c) + (float)(a).x * (float)(b).x + (float)(a).y * (float)(b).y)
#endif
#define SH2(v, i, j) __builtin_shufflevector((v), (v), (i), (j))

// ---------------------------------------------------------------------------
// Kernel 1: x_gates[t][n] = emb[seq[t]] . W_ih[n] + b_ih[n] + b_hh[n]
// f32 tiled GEMM, 128x128 tile. Block (0,0) also zeroes kernel 2's hslot
// stamps (2 parities x 2048 dwords) and the final-phase flags (256 ints) —
// this also resets state between graph replays (same stream ordering).
// ---------------------------------------------------------------------------
__global__ __launch_bounds__(256) void gemm_xgates(
    const int* __restrict__ seq, const float* __restrict__ emb,
    const float* __restrict__ Wih, const float* __restrict__ bih,
    const float* __restrict__ bhh, float* __restrict__ xg,
    unsigned int* __restrict__ hslot, int* __restrict__ flags)
{
    if (blockIdx.x == 0 && blockIdx.y == 0) {
        for (int i = threadIdx.x; i < 2 * HID; i += 256) hslot[i] = 0;
        if (threadIdx.x < NWG) flags[threadIdx.x] = 0;
    }

    constexpr int BM = 128, BN = 128, BK = 32;
    __shared__ float As[BK][BM + 4];
    __shared__ float Bs[BK][BN + 4];
    __shared__ int   srow[BM];

    const int tid = threadIdx.x;
    const int bn = blockIdx.x, bm = blockIdx.y;

    if (tid < BM) srow[tid] = seq[bm * BM + tid];
    __syncthreads();

    const int tx = tid & 15, ty = tid >> 4;
    const int c4 = tid & 7;
    const int r0 = tid >> 3;

    float acc[8][8] = {};

    for (int k0 = 0; k0 < EMB; k0 += BK) {
        #pragma unroll
        for (int i = 0; i < 4; ++i) {
            const int r = r0 + 32 * i;
            float4 av = *(const float4*)(emb + (size_t)srow[r] * EMB + k0 + 4 * c4);
            As[4*c4+0][r] = av.x; As[4*c4+1][r] = av.y;
            As[4*c4+2][r] = av.z; As[4*c4+3][r] = av.w;
            float4 bv = *(const float4*)(Wih + (size_t)(bn * BN + r) * EMB + k0 + 4 * c4);
            Bs[4*c4+0][r] = bv.x; Bs[4*c4+1][r] = bv.y;
            Bs[4*c4+2][r] = bv.z; Bs[4*c4+3][r] = bv.w;
        }
        __syncthreads();
        #pragma unroll
        for (int kk = 0; kk < BK; ++kk) {
            float a[8], b[8];
            *(float4*)&a[0] = *(const float4*)&As[kk][8*ty];
            *(float4*)&a[4] = *(const float4*)&As[kk][8*ty+4];
            *(float4*)&b[0] = *(const float4*)&Bs[kk][8*tx];
            *(float4*)&b[4] = *(const float4*)&Bs[kk][8*tx+4];
            #pragma unroll
            for (int i = 0; i < 8; ++i)
                #pragma unroll
                for (int j = 0; j < 8; ++j)
                    acc[i][j] += a[i] * b[j];
        }
        __syncthreads();
    }

    const int gm = bm * BM + 8 * ty;
    const int gn = bn * BN + 8 * tx;
    float bb[8];
    #pragma unroll
    for (int j = 0; j < 8; ++j) bb[j] = bih[gn + j] + bhh[gn + j];
    #pragma unroll
    for (int i = 0; i < 8; ++i) {
        float4 o0, o1;
        o0.x = acc[i][0] + bb[0]; o0.y = acc[i][1] + bb[1];
        o0.z = acc[i][2] + bb[2]; o0.w = acc[i][3] + bb[3];
        o1.x = acc[i][4] + bb[4]; o1.y = acc[i][5] + bb[5];
        o1.z = acc[i][6] + bb[6]; o1.w = acc[i][7] + bb[7];
        *(float4*)(xg + (size_t)(gm + i) * G4 + gn)     = o0;
        *(float4*)(xg + (size_t)(gm + i) * G4 + gn + 4) = o1;
    }
}

// ---------------------------------------------------------------------------
// L3-direct (sc0 sc1) helpers — data at the coherence point, zero cache
// maintenance.
// ---------------------------------------------------------------------------
__device__ __forceinline__ uint4 ld_u4_l3(const void* p) {
    uint4 r;
    asm volatile("global_load_dwordx4 %0, %1, off sc0 sc1\n\ts_waitcnt vmcnt(0)"
                 : "=v"(r) : "v"(p) : "memory");
    return r;
}
__device__ __forceinline__ int ld_i32_l3(const void* p) {
    int r;
    asm volatile("global_load_dword %0, %1, off sc0 sc1\n\ts_waitcnt vmcnt(0)"
                 : "=v"(r) : "v"(p) : "memory");
    return r;
}
__device__ __forceinline__ float ld_f32_l3(const void* p) {
    float r;
    asm volatile("global_load_dword %0, %1, off sc0 sc1\n\ts_waitcnt vmcnt(0)"
                 : "=v"(r) : "v"(p) : "memory");
    return r;
}
__device__ __forceinline__ void st_u32_l3(void* p, unsigned int v) {
    asm volatile("global_store_dword %0, %1, off sc0 sc1"
                 :: "v"(p), "v"(v) : "memory");
}
__device__ __forceinline__ void st_f32_l3(void* p, float v) {
    asm volatile("global_store_dword %0, %1, off sc0 sc1"
                 :: "v"(p), "v"(v) : "memory");
}
__device__ __forceinline__ void wait_vm0() {
    asm volatile("s_waitcnt vmcnt(0)" ::: "memory");
}

__device__ __forceinline__ float sigm_(float x) { return 1.0f / (1.0f + __expf(-x)); }
__device__ __forceinline__ float tanh_(float x) {
    float e = __expf(2.0f * x);
    return (e - 1.0f) / (e + 1.0f);
}

// ---------------------------------------------------------------------------
// Kernel 2: persistent LSTM recurrence, 256 wgs x 512 threads (1 wg/CU).
// Weights in LDS as f16, inner product via v_dot2_f32_f16.
// Cross-WG exchange: ONE dword per hidden unit = {stamp:u16=t+1, h:f16}.
// Poll (R8 fix): INDEPENDENT per-thread spin — back-to-back L3 dwordx4
// loads (period = 1 L3 RT, no sleep, no per-sample syncthreads; the old
// sync-per-round made every sample wait for the slowest thread and
// quantized detect latency to multiple amplified rounds). Thread ds-writes
// its 4 h values the moment its stamps match; ONE syncthreads total.
// Monotonic stamps + parity double-buffer => deadlock- and tear-free.
// ---------------------------------------------------------------------------
__global__ __launch_bounds__(512, 1) void lstm_recur(
    const float* __restrict__ Whh, const float* __restrict__ xg,
    const float* __restrict__ Wtag, const float* __restrict__ btag,
    unsigned int* __restrict__ hslot, float* __restrict__ tags,
    float* __restrict__ out, int* __restrict__ flags)
{
    __shared__ __align__(16) ushort wf16[8][4][HID];  // 128 KB f16 weights
    __shared__ __align__(16) ushort shh16[HID];       // 4 KB staged h (f16)
    __shared__ float sh_red[8];

    const int tid = threadIdx.x;
    const int wv  = tid >> 6;              // wave 0..7
    const int l   = tid & 63;              // lane
    const int bid = blockIdx.x;
    const int j   = 8 * bid + wv;          // hidden unit owned by this wave

    // One-time: W_hh rows -> f16 -> LDS. Lane l owns 8-elem chunks c8=l+64i.
    #pragma unroll
    for (int q = 0; q < 4; ++q) {
        const float* wr = Whh + (size_t)(q * HID + j) * HID;
        #pragma unroll
        for (int i = 0; i < 4; ++i) {
            const int c8 = l + 64 * i;
            float4 va = *(const float4*)(wr + 8 * c8);
            float4 vb = *(const float4*)(wr + 8 * c8 + 4);
            h4v wa = {(_Float16)va.x, (_Float16)va.y, (_Float16)va.z, (_Float16)va.w};
            h4v wb = {(_Float16)vb.x, (_Float16)vb.y, (_Float16)vb.z, (_Float16)vb.w};
            *(h4v*)&wf16[wv][q][8 * c8]     = wa;
            *(h4v*)&wf16[wv][q][8 * c8 + 4] = wb;
        }
    }

    // Independent spin until this thread's 4 stamps == target, then stage h
    // into LDS and converge with a single syncthreads.
    auto poll_stage = [&](int target, int parity) {
        const unsigned int* base = hslot + parity * HID + 4 * tid;
        const ushort tgt = (ushort)target;
        uint4 d;
        for (;;) {
            d = ld_u4_l3(base);
            if ((((ushort)(d.x >> 16)) == tgt) & (((ushort)(d.y >> 16)) == tgt) &
                (((ushort)(d.z >> 16)) == tgt) & (((ushort)(d.w >> 16)) == tgt))
                break;
        }
        ushort4 hh = {(ushort)d.x, (ushort)d.y, (ushort)d.z, (ushort)d.w};
        *(ushort4*)&shh16[4 * tid] = hh;       // 8B ds_write, contiguous
        __syncthreads();
    };

    float cst = 0.0f;
    float xg0 = xg[j], xg1 = xg[j + HID], xg2 = xg[j + 2 * HID], xg3 = xg[j + 3 * HID];

    for (int t = 0; t < SEQL; ++t) {
        if (t > 0) poll_stage(t, (t - 1) & 1);
        else       __syncthreads();            // weights-in-LDS ready

        // Prefetch next step's xg; completes during the dot compute.
        const int tn = (t + 1 < SEQL) ? t + 1 : t;
        const size_t xb = (size_t)tn * G4 + j;
        const float nx0 = xg[xb];
        const float nx1 = xg[xb + HID];
        const float nx2 = xg[xb + 2 * HID];
        const float nx3 = xg[xb + 3 * HID];

        float s0 = 0.f, s1 = 0.f, s2 = 0.f, s3 = 0.f;
        if (t > 0) {
            #pragma unroll
            for (int r = 0; r < 4; ++r) {
                const int kc = 8 * (l + 64 * r);
                h4v ha = *(const h4v*)&shh16[kc];
                h4v hb = *(const h4v*)&shh16[kc + 4];
                h2v h0 = SH2(ha, 0, 1), h1 = SH2(ha, 2, 3);
                h2v h2 = SH2(hb, 0, 1), h3 = SH2(hb, 2, 3);
                h4v w;
                w = *(const h4v*)&wf16[wv][0][kc];
                s0 = DOT2(SH2(w,0,1), h0, s0); s0 = DOT2(SH2(w,2,3), h1, s0);
                w = *(const h4v*)&wf16[wv][0][kc + 4];
                s0 = DOT2(SH2(w,0,1), h2, s0); s0 = DOT2(SH2(w,2,3), h3, s0);
                w = *(const h4v*)&wf16[wv][1][kc];
                s1 = DOT2(SH2(w,0,1), h0, s1); s1 = DOT2(SH2(w,2,3), h1, s1);
                w = *(const h4v*)&wf16[wv][1][kc + 4];
                s1 = DOT2(SH2(w,0,1), h2, s1); s1 = DOT2(SH2(w,2,3), h3, s1);
                w = *(const h4v*)&wf16[wv][2][kc];
                s2 = DOT2(SH2(w,0,1), h0, s2); s2 = DOT2(SH2(w,2,3), h1, s2);
                w = *(const h4v*)&wf16[wv][2][kc + 4];
                s2 = DOT2(SH2(w,0,1), h2, s2); s2 = DOT2(SH2(w,2,3), h3, s2);
                w = *(const h4v*)&wf16[wv][3][kc];
                s3 = DOT2(SH2(w,0,1), h0, s3); s3 = DOT2(SH2(w,2,3), h1, s3);
                w = *(const h4v*)&wf16[wv][3][kc + 4];
                s3 = DOT2(SH2(w,0,1), h2, s3); s3 = DOT2(SH2(w,2,3), h3, s3);
            }
        }
        #pragma unroll
        for (int m = 1; m < 64; m <<= 1) {
            s0 += __shfl_xor(s0, m);
            s1 += __shfl_xor(s1, m);
            s2 += __shfl_xor(s2, m);
            s3 += __shfl_xor(s3, m);
        }
        const float gi = sigm_(s0 + xg0);
        const float gf = sigm_(s1 + xg1);
        const float gg = tanh_(s2 + xg2);
        const float go = sigm_(s3 + xg3);
        cst = gf * cst + gi * gg;
        const float h = go * tanh_(cst);

        if (l == 0) {
            _Float16 hf = (_Float16)h;
            unsigned int d = ((unsigned int)(ushort)(t + 1) << 16)
                           | (unsigned int)__builtin_bit_cast(ushort, hf);
            st_u32_l3(hslot + (t & 1) * HID + j, d);   // data+stamp, one store
        }

        xg0 = nx0; xg1 = nx1; xg2 = nx2; xg3 = nx3;
    }

    // ---- final h, tag projection (wgs 0..49, one tag row each) ----
    poll_stage(SEQL, (SEQL - 1) & 1);          // stage h_1023 (f16) into LDS
    if (bid < NTAG) {
        h4v hv4 = *(const h4v*)&shh16[4 * tid];
        float4 w4 = *(const float4*)(Wtag + (size_t)bid * HID + 4 * tid);
        float part = w4.x * (float)hv4.x + w4.y * (float)hv4.y
                   + w4.z * (float)hv4.z + w4.w * (float)hv4.w;
        #pragma unroll
        for (int m = 1; m < 64; m <<= 1) part += __shfl_xor(part, m);
        if (l == 0) sh_red[wv] = part;
    }
    __syncthreads();
    if (bid < NTAG && tid == 0) {
        float s = 0.f;
        #pragma unroll
        for (int i = 0; i < 8; ++i) s += sh_red[i];
        st_f32_l3(tags + bid, s + btag[bid]);
    }
    wait_vm0();
    __syncthreads();
    if (tid == 0) st_u32_l3((unsigned int*)(flags + bid), 1u);

    // ---- log_softmax on wg 0 ----
    if (bid == 0) {
        for (;;) {
            int ok = 1;
            if (tid < NTAG) ok = (ld_i32_l3(flags + tid) >= 1);
            if (__syncthreads_and(ok)) break;
            __builtin_amdgcn_s_sleep(1);
        }
        if (tid < 64) {
            float v = (tid < NTAG) ? ld_f32_l3(tags + tid) : -3.0e38f;
            float mx = v;
            #pragma unroll
            for (int m = 1; m < 64; m <<= 1) mx = fmaxf(mx, __shfl_xor(mx, m));
            float e = (tid < NTAG) ? __expf(v - mx) : 0.f;
            float se = e;
            #pragma unroll
            for (int m = 1; m < 64; m <<= 1) se += __shfl_xor(se, m);
            if (tid < NTAG) out[tid] = v - mx - __logf(se);
        }
    }
}

// ---------------------------------------------------------------------------
extern "C" void kernel_launch(void* const* d_in, const int* in_sizes, int n_in,
                              void* d_out, int out_size, void* d_ws, size_t ws_size,
                              hipStream_t stream)
{
    const int*   seq  = (const int*)d_in[0];
    const float* emb  = (const float*)d_in[1];
    const float* Wih  = (const float*)d_in[2];
    const float* Whh  = (const float*)d_in[3];
    const float* bih  = (const float*)d_in[4];
    const float* bhh  = (const float*)d_in[5];
    const float* Wtag = (const float*)d_in[6];
    const float* btag = (const float*)d_in[7];
    float* out = (float*)d_out;

    float* xg = (float*)d_ws;                              // 32 MiB
    unsigned int* hslot = (unsigned int*)(xg + (size_t)SEQL * G4);  // 2*2048 u32
    float* tags  = (float*)(hslot + 2 * HID);              // 50 f32 (pad 64)
    int*   flags = (int*)(tags + 64);                      // 256 ints

    dim3 g1(G4 / 128, SEQL / 128);                         // (64, 8)
    gemm_xgates<<<g1, 256, 0, stream>>>(seq, emb, Wih, bih, bhh, xg, hslot, flags);

    void* args[] = {(void*)&Whh, (void*)&xg, (void*)&Wtag, (void*)&btag,
                    (void*)&hslot, (void*)&tags, (void*)&out, (void*)&flags};
    hipLaunchCooperativeKernel((void*)lstm_recur, dim3(NWG), dim3(512),
                               args, 0, stream);
}

// Round 10
// 2833.560 us; speedup vs baseline: 25.3385x; 1.1886x over previous
//
#include <hip/hip_runtime.h>

#define SEQL 1024
#define EMB  2048
#define HID  2048
#define G4   8192   // 4*HID
#define NTAG 50
#define NWG  256

typedef _Float16 h2v __attribute__((ext_vector_type(2)));
typedef _Float16 h4v __attribute__((ext_vector_type(4)));
typedef __attribute__((ext_vector_type(8))) short bf16x8;   // 8 bf16 = 4 VGPR
typedef __attribute__((ext_vector_type(4))) float f32x4;

#if __has_builtin(__builtin_amdgcn_fdot2)
#define DOT2(a, b, c) __builtin_amdgcn_fdot2((a), (b), (c), false)
#else
#define DOT2(a, b, c) ((c) + (float)(a).x * (float)(b).x + (float)(a).y * (float)(b).y)
#endif
#define SH2(v, i, j) __builtin_shufflevector((v), (v), (i), (j))

__device__ __forceinline__ ushort f2bf_rne(float f) {
    unsigned u = __float_as_uint(f);
    unsigned r = (u + 0x7fffu + ((u >> 16) & 1u)) >> 16;   // round-nearest-even
    return (ushort)r;
}

// ---------------------------------------------------------------------------
// Kernel 1: x_gates[t][n] = emb[seq[t]] . W_ih[n] + b_ih[n] + b_hh[n]
// bf16 MFMA GEMM: M=1024, N=8192, K=2048. 128x128 tile, BK=64, 256 threads
// (4 waves, 2x2 of 64x64). f32 inputs converted to bf16 (RNE) during LDS
// staging. LDS rows are 128B-strided -> chunk-XOR swizzle (c ^= row&7, 16B
// chunks) makes the 16-lane column read <=2-way bank aliased (free, m136).
// mfma_f32_16x16x32_bf16: A lane(m=l&15, k=(l>>4)*8+e), B^T trick (load
// Wih[n][k] run as the B operand's column n), C/D col=l&15 row=(l>>4)*4+e.
// Block (0,0) also zeroes kernel 2's hslot stamps + flags (graph-replay
// reset, stream-ordered before lstm_recur).
// ---------------------------------------------------------------------------
__global__ __launch_bounds__(256) void gemm_xgates(
    const int* __restrict__ seq, const float* __restrict__ emb,
    const float* __restrict__ Wih, const float* __restrict__ bih,
    const float* __restrict__ bhh, float* __restrict__ xg,
    unsigned int* __restrict__ hslot, int* __restrict__ flags)
{
    if (blockIdx.x == 0 && blockIdx.y == 0) {
        for (int i = threadIdx.x; i < 2 * HID; i += 256) hslot[i] = 0;
        if (threadIdx.x < NWG) flags[threadIdx.x] = 0;
    }

    constexpr int BM = 128, BN = 128, BK = 64;
    __shared__ __align__(16) ushort Al[BM][BK];   // bf16, chunk-XOR swizzled
    __shared__ __align__(16) ushort Bl[BN][BK];
    __shared__ int srow[BM];

    const int tid = threadIdx.x;
    const int bn = blockIdx.x, bm = blockIdx.y;

    if (tid < BM) srow[tid] = seq[bm * BM + tid];
    __syncthreads();

    const int lane = tid & 63;
    const int wave = tid >> 6;          // 0..3
    const int wm = (wave >> 1) * 64;    // wave's C sub-block origin
    const int wn = (wave & 1) * 64;
    const int srw = tid >> 1;           // staging row 0..127
    const int skh = (tid & 1) * 32;     // staging k-offset 0/32
    const int cb  = skh >> 3;           // base chunk 0/4

    f32x4 acc[4][4] = {};

    for (int k0 = 0; k0 < EMB; k0 += BK) {
        // ---- stage A,B: 32 f32 each -> bf16 -> swizzled LDS ----
        const float* ap = emb + (size_t)srow[srw] * EMB + k0 + skh;
        const float* bp = Wih + (size_t)(bn * BN + srw) * EMB + k0 + skh;
        #pragma unroll
        for (int c = 0; c < 4; ++c) {
            float4 a0 = *(const float4*)(ap + 8 * c);
            float4 a1 = *(const float4*)(ap + 8 * c + 4);
            bf16x8 av;
            av[0] = (short)f2bf_rne(a0.x); av[1] = (short)f2bf_rne(a0.y);
            av[2] = (short)f2bf_rne(a0.z); av[3] = (short)f2bf_rne(a0.w);
            av[4] = (short)f2bf_rne(a1.x); av[5] = (short)f2bf_rne(a1.y);
            av[6] = (short)f2bf_rne(a1.z); av[7] = (short)f2bf_rne(a1.w);
            *(bf16x8*)&Al[srw][8 * ((cb + c) ^ (srw & 7))] = av;

            float4 b0 = *(const float4*)(bp + 8 * c);
            float4 b1 = *(const float4*)(bp + 8 * c + 4);
            bf16x8 bv;
            bv[0] = (short)f2bf_rne(b0.x); bv[1] = (short)f2bf_rne(b0.y);
            bv[2] = (short)f2bf_rne(b0.z); bv[3] = (short)f2bf_rne(b0.w);
            bv[4] = (short)f2bf_rne(b1.x); bv[5] = (short)f2bf_rne(b1.y);
            bv[6] = (short)f2bf_rne(b1.z); bv[7] = (short)f2bf_rne(b1.w);
            *(bf16x8*)&Bl[srw][8 * ((cb + c) ^ (srw & 7))] = bv;
        }
        __syncthreads();

        // ---- compute: 2 k-substeps of 32 ----
        const int kg = lane >> 4;        // k-group 0..3
        #pragma unroll
        for (int ks = 0; ks < 2; ++ks) {
            bf16x8 af[4], bfr[4];
            #pragma unroll
            for (int f = 0; f < 4; ++f) {
                const int ra = wm + f * 16 + (lane & 15);
                af[f]  = *(const bf16x8*)&Al[ra][8 * ((ks * 4 + kg) ^ (ra & 7))];
                const int rb = wn + f * 16 + (lane & 15);
                bfr[f] = *(const bf16x8*)&Bl[rb][8 * ((ks * 4 + kg) ^ (rb & 7))];
            }
            #pragma unroll
            for (int i = 0; i < 4; ++i)
                #pragma unroll
                for (int j2 = 0; j2 < 4; ++j2)
                    acc[i][j2] = __builtin_amdgcn_mfma_f32_16x16x32_bf16(
                        af[i], bfr[j2], acc[i][j2], 0, 0, 0);
        }
        __syncthreads();
    }

    // ---- epilogue: bias + store (C/D: col=l&15, row=(l>>4)*4+e) ----
    float bb[4];
    #pragma unroll
    for (int j2 = 0; j2 < 4; ++j2) {
        const int col = bn * BN + wn + j2 * 16 + (lane & 15);
        bb[j2] = bih[col] + bhh[col];
    }
    #pragma unroll
    for (int i = 0; i < 4; ++i) {
        #pragma unroll
        for (int e = 0; e < 4; ++e) {
            const int row = bm * BM + wm + i * 16 + (lane >> 4) * 4 + e;
            #pragma unroll
            for (int j2 = 0; j2 < 4; ++j2) {
                const int col = bn * BN + wn + j2 * 16 + (lane & 15);
                xg[(size_t)row * G4 + col] = acc[i][j2][e] + bb[j2];
            }
        }
    }
}

// ---------------------------------------------------------------------------
// L3-direct (sc0 sc1) helpers — data at the coherence point, zero cache
// maintenance.
// ---------------------------------------------------------------------------
__device__ __forceinline__ uint4 ld_u4_l3(const void* p) {
    uint4 r;
    asm volatile("global_load_dwordx4 %0, %1, off sc0 sc1\n\ts_waitcnt vmcnt(0)"
                 : "=v"(r) : "v"(p) : "memory");
    return r;
}
__device__ __forceinline__ int ld_i32_l3(const void* p) {
    int r;
    asm volatile("global_load_dword %0, %1, off sc0 sc1\n\ts_waitcnt vmcnt(0)"
                 : "=v"(r) : "v"(p) : "memory");
    return r;
}
__device__ __forceinline__ float ld_f32_l3(const void* p) {
    float r;
    asm volatile("global_load_dword %0, %1, off sc0 sc1\n\ts_waitcnt vmcnt(0)"
                 : "=v"(r) : "v"(p) : "memory");
    return r;
}
__device__ __forceinline__ void st_u32_l3(void* p, unsigned int v) {
    asm volatile("global_store_dword %0, %1, off sc0 sc1"
                 :: "v"(p), "v"(v) : "memory");
}
__device__ __forceinline__ void st_f32_l3(void* p, float v) {
    asm volatile("global_store_dword %0, %1, off sc0 sc1"
                 :: "v"(p), "v"(v) : "memory");
}
__device__ __forceinline__ void wait_vm0() {
    asm volatile("s_waitcnt vmcnt(0)" ::: "memory");
}

__device__ __forceinline__ float sigm_(float x) { return 1.0f / (1.0f + __expf(-x)); }
__device__ __forceinline__ float tanh_(float x) {
    float e = __expf(2.0f * x);
    return (e - 1.0f) / (e + 1.0f);
}

// ---------------------------------------------------------------------------
// Kernel 2: persistent LSTM recurrence (unchanged from R9 — verified 3.0 ms).
// 256 wgs x 512 threads (1 wg/CU); f16 weights in LDS; v_dot2_f32_f16 dots;
// one dword {stamp:u16, h:f16} per unit; independent per-thread spin.
// ---------------------------------------------------------------------------
__global__ __launch_bounds__(512, 1) void lstm_recur(
    const float* __restrict__ Whh, const float* __restrict__ xg,
    const float* __restrict__ Wtag, const float* __restrict__ btag,
    unsigned int* __restrict__ hslot, float* __restrict__ tags,
    float* __restrict__ out, int* __restrict__ flags)
{
    __shared__ __align__(16) ushort wf16[8][4][HID];  // 128 KB f16 weights
    __shared__ __align__(16) ushort shh16[HID];       // 4 KB staged h (f16)
    __shared__ float sh_red[8];

    const int tid = threadIdx.x;
    const int wv  = tid >> 6;              // wave 0..7
    const int l   = tid & 63;              // lane
    const int bid = blockIdx.x;
    const int j   = 8 * bid + wv;          // hidden unit owned by this wave

    // One-time: W_hh rows -> f16 -> LDS. Lane l owns 8-elem chunks c8=l+64i.
    #pragma unroll
    for (int q = 0; q < 4; ++q) {
        const float* wr = Whh + (size_t)(q * HID + j) * HID;
        #pragma unroll
        for (int i = 0; i < 4; ++i) {
            const int c8 = l + 64 * i;
            float4 va = *(const float4*)(wr + 8 * c8);
            float4 vb = *(const float4*)(wr + 8 * c8 + 4);
            h4v wa = {(_Float16)va.x, (_Float16)va.y, (_Float16)va.z, (_Float16)va.w};
            h4v wb = {(_Float16)vb.x, (_Float16)vb.y, (_Float16)vb.z, (_Float16)vb.w};
            *(h4v*)&wf16[wv][q][8 * c8]     = wa;
            *(h4v*)&wf16[wv][q][8 * c8 + 4] = wb;
        }
    }

    // Independent spin until this thread's 4 stamps == target, then stage h
    // into LDS and converge with a single syncthreads.
    auto poll_stage = [&](int target, int parity) {
        const unsigned int* base = hslot + parity * HID + 4 * tid;
        const ushort tgt = (ushort)target;
        uint4 d;
        for (;;) {
            d = ld_u4_l3(base);
            if ((((ushort)(d.x >> 16)) == tgt) & (((ushort)(d.y >> 16)) == tgt) &
                (((ushort)(d.z >> 16)) == tgt) & (((ushort)(d.w >> 16)) == tgt))
                break;
        }
        ushort4 hh = {(ushort)d.x, (ushort)d.y, (ushort)d.z, (ushort)d.w};
        *(ushort4*)&shh16[4 * tid] = hh;       // 8B ds_write, contiguous
        __syncthreads();
    };

    float cst = 0.0f;
    float xg0 = xg[j], xg1 = xg[j + HID], xg2 = xg[j + 2 * HID], xg3 = xg[j + 3 * HID];

    for (int t = 0; t < SEQL; ++t) {
        if (t > 0) poll_stage(t, (t - 1) & 1);
        else       __syncthreads();            // weights-in-LDS ready

        // Prefetch next step's xg; completes during the dot compute.
        const int tn = (t + 1 < SEQL) ? t + 1 : t;
        const size_t xb = (size_t)tn * G4 + j;
        const float nx0 = xg[xb];
        const float nx1 = xg[xb + HID];
        const float nx2 = xg[xb + 2 * HID];
        const float nx3 = xg[xb + 3 * HID];

        float s0 = 0.f, s1 = 0.f, s2 = 0.f, s3 = 0.f;
        if (t > 0) {
            #pragma unroll
            for (int r = 0; r < 4; ++r) {
                const int kc = 8 * (l + 64 * r);
                h4v ha = *(const h4v*)&shh16[kc];
                h4v hb = *(const h4v*)&shh16[kc + 4];
                h2v h0 = SH2(ha, 0, 1), h1 = SH2(ha, 2, 3);
                h2v h2 = SH2(hb, 0, 1), h3 = SH2(hb, 2, 3);
                h4v w;
                w = *(const h4v*)&wf16[wv][0][kc];
                s0 = DOT2(SH2(w,0,1), h0, s0); s0 = DOT2(SH2(w,2,3), h1, s0);
                w = *(const h4v*)&wf16[wv][0][kc + 4];
                s0 = DOT2(SH2(w,0,1), h2, s0); s0 = DOT2(SH2(w,2,3), h3, s0);
                w = *(const h4v*)&wf16[wv][1][kc];
                s1 = DOT2(SH2(w,0,1), h0, s1); s1 = DOT2(SH2(w,2,3), h1, s1);
                w = *(const h4v*)&wf16[wv][1][kc + 4];
                s1 = DOT2(SH2(w,0,1), h2, s1); s1 = DOT2(SH2(w,2,3), h3, s1);
                w = *(const h4v*)&wf16[wv][2][kc];
                s2 = DOT2(SH2(w,0,1), h0, s2); s2 = DOT2(SH2(w,2,3), h1, s2);
                w = *(const h4v*)&wf16[wv][2][kc + 4];
                s2 = DOT2(SH2(w,0,1), h2, s2); s2 = DOT2(SH2(w,2,3), h3, s2);
                w = *(const h4v*)&wf16[wv][3][kc];
                s3 = DOT2(SH2(w,0,1), h0, s3); s3 = DOT2(SH2(w,2,3), h1, s3);
                w = *(const h4v*)&wf16[wv][3][kc + 4];
                s3 = DOT2(SH2(w,0,1), h2, s3); s3 = DOT2(SH2(w,2,3), h3, s3);
            }
        }
        #pragma unroll
        for (int m = 1; m < 64; m <<= 1) {
            s0 += __shfl_xor(s0, m);
            s1 += __shfl_xor(s1, m);
            s2 += __shfl_xor(s2, m);
            s3 += __shfl_xor(s3, m);
        }
        const float gi = sigm_(s0 + xg0);
        const float gf = sigm_(s1 + xg1);
        const float gg = tanh_(s2 + xg2);
        const float go = sigm_(s3 + xg3);
        cst = gf * cst + gi * gg;
        const float h = go * tanh_(cst);

        if (l == 0) {
            _Float16 hf = (_Float16)h;
            unsigned int d = ((unsigned int)(ushort)(t + 1) << 16)
                           | (unsigned int)__builtin_bit_cast(ushort, hf);
            st_u32_l3(hslot + (t & 1) * HID + j, d);   // data+stamp, one store
        }

        xg0 = nx0; xg1 = nx1; xg2 = nx2; xg3 = nx3;
    }

    // ---- final h, tag projection (wgs 0..49, one tag row each) ----
    poll_stage(SEQL, (SEQL - 1) & 1);          // stage h_1023 (f16) into LDS
    if (bid < NTAG) {
        h4v hv4 = *(const h4v*)&shh16[4 * tid];
        float4 w4 = *(const float4*)(Wtag + (size_t)bid * HID + 4 * tid);
        float part = w4.x * (float)hv4.x + w4.y * (float)hv4.y
                   + w4.z * (float)hv4.z + w4.w * (float)hv4.w;
        #pragma unroll
        for (int m = 1; m < 64; m <<= 1) part += __shfl_xor(part, m);
        if (l == 0) sh_red[wv] = part;
    }
    __syncthreads();
    if (bid < NTAG && tid == 0) {
        float s = 0.f;
        #pragma unroll
        for (int i = 0; i < 8; ++i) s += sh_red[i];
        st_f32_l3(tags + bid, s + btag[bid]);
    }
    wait_vm0();
    __syncthreads();
    if (tid == 0) st_u32_l3((unsigned int*)(flags + bid), 1u);

    // ---- log_softmax on wg 0 ----
    if (bid == 0) {
        for (;;) {
            int ok = 1;
            if (tid < NTAG) ok = (ld_i32_l3(flags + tid) >= 1);
            if (__syncthreads_and(ok)) break;
            __builtin_amdgcn_s_sleep(1);
        }
        if (tid < 64) {
            float v = (tid < NTAG) ? ld_f32_l3(tags + tid) : -3.0e38f;
            float mx = v;
            #pragma unroll
            for (int m = 1; m < 64; m <<= 1) mx = fmaxf(mx, __shfl_xor(mx, m));
            float e = (tid < NTAG) ? __expf(v - mx) : 0.f;
            float se = e;
            #pragma unroll
            for (int m = 1; m < 64; m <<= 1) se += __shfl_xor(se, m);
            if (tid < NTAG) out[tid] = v - mx - __logf(se);
        }
    }
}

// ---------------------------------------------------------------------------
extern "C" void kernel_launch(void* const* d_in, const int* in_sizes, int n_in,
                              void* d_out, int out_size, void* d_ws, size_t ws_size,
                              hipStream_t stream)
{
    const int*   seq  = (const int*)d_in[0];
    const float* emb  = (const float*)d_in[1];
    const float* Wih  = (const float*)d_in[2];
    const float* Whh  = (const float*)d_in[3];
    const float* bih  = (const float*)d_in[4];
    const float* bhh  = (const float*)d_in[5];
    const float* Wtag = (const float*)d_in[6];
    const float* btag = (const float*)d_in[7];
    float* out = (float*)d_out;

    float* xg = (float*)d_ws;                              // 32 MiB
    unsigned int* hslot = (unsigned int*)(xg + (size_t)SEQL * G4);  // 2*2048 u32
    float* tags  = (float*)(hslot + 2 * HID);              // 50 f32 (pad 64)
    int*   flags = (int*)(tags + 64);                      // 256 ints

    dim3 g1(G4 / 128, SEQL / 128);                         // (64, 8)
    gemm_xgates<<<g1, 256, 0, stream>>>(seq, emb, Wih, bih, bhh, xg, hslot, flags);

    void* args[] = {(void*)&Whh, (void*)&xg, (void*)&Wtag, (void*)&btag,
                    (void*)&hslot, (void*)&tags, (void*)&out, (void*)&flags};
    hipLaunchCooperativeKernel((void*)lstm_recur, dim3(NWG), dim3(512),
                               args, 0, stream);
}